// Round 4
// baseline (542.071 us; speedup 1.0000x reference)
//
#include <hip/hip_runtime.h>
#include <math.h>

typedef unsigned short u16;
typedef unsigned int   u32;

typedef __attribute__((ext_vector_type(8))) _Float16 f16x8;
typedef __attribute__((ext_vector_type(4))) float    f32x4;

// ---------- constants ----------
#define NB   2
#define C    256
#define H    96
#define W    96
#define HW   (H*W)          // 9216
#define HP   98
#define OC   256
#define KDIM (9*C)          // 2304
#define NS   (NB*HW)        // 18432 spatial columns
#define NCHUNK 8            // channel chunks in stage-A conv

// ws layout (bytes) — same as round 3
#define PARTIAL_OFF  0                          // 8*2*21*9216 fp32  = 12386304
#define OFFBUF_OFF   12386304                   // 2*18*9216 fp32    = 1327104
#define AD2_OFF      13713408                   // 2*3*9216 fp32     = 221184
#define XP_OFF       13934592                   // 2*98*98*256 fp32  = 19668992
#define AHI_OFF      33603584                   // 256*2304 f16      = 1179648
#define ALO_OFF      34783232                   // 256*2304 f16      = 1179648
#define IDX_OFF      35962880                   // 9*18432*4 int     = 2654208
#define G_OFF        38617088                   // 9*18432*4 fp32    = 2654208

__device__ __forceinline__ u16 h2u(_Float16 h) {
  return __builtin_bit_cast(unsigned short, h);
}
__device__ __forceinline__ void split16(float v, u16& hi, u16& lo) {
  _Float16 h = (_Float16)v;        // v_cvt_f16_f32, RNE
  float r = v - (float)h;          // exact residual
  _Float16 l = (_Float16)r;
  hi = h2u(h); lo = h2u(l);
}
// LDS-only barrier: waits lgkmcnt(0) but does NOT drain vmcnt — keeps global
// prefetches in flight across the barrier (CK block_sync_lds pattern).
__device__ __forceinline__ void sync_lds() {
  asm volatile("s_waitcnt lgkmcnt(0)\n\ts_barrier" ::: "memory");
}

// ---------- stage A: 21-ch 3x3 conv over 256c, fp32 ----------
// grid 576 = n(2)*tile(36 of 16x16)*chunk(8); block 256 (4 waves), 1 px/thread
// weights read with block-uniform addresses -> scalar loads (SGPR operands)
__global__ __launch_bounds__(256) void conv_small(
    const float* __restrict__ x, const float* __restrict__ w_p,
    const float* __restrict__ w_ad, float* __restrict__ partial) {
  int bx = blockIdx.x;
  int chunk = bx & 7;
  int r  = bx >> 3;
  int tile = r % 36;
  int n    = r / 36;
  int h0 = (tile / 6) * 16, w0 = (tile % 6) * 16;
  int c0 = chunk * 32;
  int tid = threadIdx.x;
  int row = tid >> 4, col = tid & 15;
  int h = h0 + row, w = w0 + col;

  float acc[21];
  #pragma unroll
  for (int ch = 0; ch < 21; ch++) acc[ch] = 0.f;

  const float* xn = x + (size_t)(n*C + c0) * HW;
  for (int cc = 0; cc < 32; cc++) {
    const float* xc = xn + cc * HW;
    int gc = c0 + cc;                       // uniform across block
    float xr[9];
    #pragma unroll
    for (int di = 0; di < 3; di++) {
      int hg = h + di - 1;
      bool hok = ((unsigned)hg < 96u);
      #pragma unroll
      for (int dj = 0; dj < 3; dj++) {
        int wg = w + dj - 1;
        bool ok = hok && ((unsigned)wg < 96u);
        xr[di*3+dj] = ok ? xc[hg*W + wg] : 0.f;
      }
    }
    #pragma unroll
    for (int ch = 0; ch < 18; ch++) {
      const float* wv = w_p + ((size_t)ch*C + gc)*9;    // uniform -> s_load
      #pragma unroll
      for (int t = 0; t < 9; t++)
        acc[ch] = fmaf(xr[t], wv[t], acc[ch]);
    }
    #pragma unroll
    for (int ch = 0; ch < 3; ch++) {
      const float* wv = w_ad + ((size_t)ch*C + gc)*9;   // uniform -> s_load
      #pragma unroll
      for (int t = 0; t < 9; t++)
        acc[18+ch] = fmaf(xr[t], wv[t], acc[18+ch]);
    }
  }
  #pragma unroll
  for (int ch = 0; ch < 21; ch++)
    partial[((chunk*2 + n)*21 + ch)*HW + h*W + w] = acc[ch];
}

// ---------- reduce partials, add bias, sigmoid for ad ----------
__global__ __launch_bounds__(256) void reduce_small(
    const float* __restrict__ partial, const float* __restrict__ b_p,
    const float* __restrict__ b_ad, float* __restrict__ off_buf,
    float* __restrict__ ad2_buf) {
  int e = blockIdx.x * 256 + threadIdx.x;
  if (e >= NB*21*HW) return;
  int n  = e / (21*HW);
  int r  = e % (21*HW);
  int ch = r / HW;
  int hw = r % HW;
  float s = 0.f;
  #pragma unroll
  for (int chunk = 0; chunk < NCHUNK; chunk++)
    s += partial[((chunk*2 + n)*21 + ch)*HW + hw];
  if (ch < 18) {
    off_buf[(n*18 + ch)*HW + hw] = s + b_p[ch];
  } else {
    float z = s + b_ad[ch - 18];
    ad2_buf[(n*3 + (ch-18))*HW + hw] = 2.0f / (1.0f + expf(z));   // (1-sigmoid)*DIL
  }
}

// ---------- NCHW fp32 -> padded NHWC fp32 (borders pre-zeroed by memset) ----------
__global__ __launch_bounds__(256) void pad_pack(
    const float* __restrict__ x, float* __restrict__ xp) {
  __shared__ float ts[64][65];
  int bx = blockIdx.x;
  int n = bx / 576; int r = bx % 576;
  int cb = r / 144; int hwb = r % 144;
  int c0 = cb * 64, hw0 = hwb * 64;
  int tid = threadIdx.x;
  int ii = tid & 63; int cl4 = tid >> 6;
  #pragma unroll
  for (int r2 = 0; r2 < 16; r2++) {
    int c_l = cl4*16 + r2;
    ts[c_l][ii] = x[(size_t)(n*C + c0 + c_l)*HW + hw0 + ii];
  }
  __syncthreads();
  int hw = hw0 + ii;
  int h = hw / W, w = hw % W;
  float* dst = xp + ((size_t)(n*HP + h + 1)*HP + (w + 1))*C + c0 + cl4*16;
  #pragma unroll
  for (int q = 0; q < 4; q++) {
    *(float4*)(dst + q*4) = make_float4(ts[cl4*16 + q*4 + 0][ii], ts[cl4*16 + q*4 + 1][ii],
                                        ts[cl4*16 + q*4 + 2][ii], ts[cl4*16 + q*4 + 3][ii]);
  }
}

// ---------- repack + split w_conv [o][c][k] -> A_hi/A_lo [o][k*256+c] f16 ----------
__global__ __launch_bounds__(256) void pack_A(
    const float* __restrict__ w_conv, u16* __restrict__ A_hi, u16* __restrict__ A_lo) {
  int e = blockIdx.x * 256 + threadIdx.x;      // < 256*2304
  int o = e / KDIM; int r = e % KDIM; int k = r >> 8; int c = r & 255;
  float a = w_conv[(o*C + c)*9 + k];
  u16 hi, lo; split16(a, hi, lo);
  A_hi[e] = hi; A_lo[e] = lo;
}

// ---------- bilinear taps: 4 indices + 4 weights per (s, k) ----------
__global__ __launch_bounds__(256) void make_taps(
    const float* __restrict__ off_buf, const float* __restrict__ ad2_buf,
    int* __restrict__ idx_arr, float* __restrict__ g_arr) {
  int e = blockIdx.x * 256 + threadIdx.x;      // < 9*18432
  int k = e / NS; int s = e % NS;
  int n = s / HW; int hw = s % HW;
  int h = hw / W, w = hw % W;
  float ri = (float)(k / 3) - 1.0f, rj = (float)(k % 3) - 1.0f;
  float offx = off_buf[(n*18 + k)*HW + hw];
  float offy = off_buf[(n*18 + k + 9)*HW + hw];
  float a2   = ad2_buf[(n*3 + (k % 3))*HW + hw];
  float px = (float)(h + 1) + ri + offx + a2 * ri;
  float py = (float)(w + 1) + rj + offy + a2 * rj;
  float fx = floorf(px), fy = floorf(py);
  int qltx = min(max((int)fx, 0), 97);
  int qlty = min(max((int)fy, 0), 97);
  int qrbx = min(max((int)fx + 1, 0), 97);
  int qrby = min(max((int)fy + 1, 0), 97);
  bool mx = (px < 1.0f) || (px > 96.0f);
  bool my = (py < 1.0f) || (py > 96.0f);
  float pxm = mx ? fx : px;
  float pym = my ? fy : py;
  pxm = fminf(fmaxf(pxm, 0.f), 97.f);
  pym = fminf(fmaxf(pym, 0.f), 97.f);
  float glx = 1.0f + ((float)qltx - pxm);
  float grx = 1.0f - ((float)qrbx - pxm);
  float gly = 1.0f + ((float)qlty - pym);
  float gry = 1.0f - ((float)qrby - pym);
  int base = n * HP * HP * C;
  int4 qi;
  qi.x = base + (qltx*HP + qlty)*C;   // lt
  qi.y = base + (qrbx*HP + qrby)*C;   // rb
  qi.z = base + (qltx*HP + qrby)*C;   // lb
  qi.w = base + (qrbx*HP + qlty)*C;   // rt
  float4 gg = make_float4(glx*gly, grx*gry, glx*gry, grx*gly);
  *(int4*)(idx_arr + (size_t)e*4) = qi;
  *(float4*)(g_arr  + (size_t)e*4) = gg;
}

// ---------- fused gather + split-f16 MFMA GEMM, software-pipelined ----------
// C[o,s] = sum_kc A[o,kc]*B[kc,s]; 3-term split-f16. Tile M=128, N=32, Kstep=32.
// grid 1152 = mo(2) * sb(576); block 256 (4 waves: mw in {0,1} x 64 o, nw in {0,1} x 16 s)
// Pipeline: idx/g prefetch 2 iters ahead; taps + A frags 1 iter ahead implicit via
// single-barrier double-buffered B LDS (sync_lds keeps vmcnt in flight).
__global__ __launch_bounds__(256, 3) void gemm_def(
    const u16* __restrict__ A_hi, const u16* __restrict__ A_lo,
    const float* __restrict__ xp,
    const int* __restrict__ idx_arr, const float* __restrict__ g_arr,
    float* __restrict__ out) {
  __shared__ u16 Bh[2][32*40];
  __shared__ u16 Bl[2][32*40];
  int bx = blockIdx.x;
  int mo = bx & 1; int sb = bx >> 1;
  int o0 = mo * 128; int s0 = sb * 32;
  int n = s0 / HW; int hw0 = s0 % HW;
  int tid = threadIdx.x;
  int wave = tid >> 6, lane = tid & 63;
  int l16 = lane & 15, quad = lane >> 4;
  int mw = wave >> 1, nw = wave & 1;

  // B-build mapping: 32 s-rows x 8 channel-quads (4 floats each) -> lanes of a
  // tap load cover 8 rows x 128B contiguous (full cache lines).
  int s_l = tid >> 3, cq = tid & 7;
  int sg = s0 + s_l;
  int csel = cq * 4;

  // per-lane A row pointers (4 m-frags, hi+lo)
  const u16* ah[4]; const u16* al[4];
  #pragma unroll
  for (int mi = 0; mi < 4; mi++) {
    int o = o0 + mw*64 + mi*16 + l16;
    ah[mi] = A_hi + (size_t)o * KDIM + quad*8;
    al[mi] = A_lo + (size_t)o * KDIM + quad*8;
  }

  f32x4 acc[4];
  f32x4 z4 = {0.f, 0.f, 0.f, 0.f};
  #pragma unroll
  for (int mi = 0; mi < 4; mi++) acc[mi] = z4;

  // ---- prologue: it=0 taps + idx chain ----
  int4   qiN = *(const int4*)(idx_arr + (size_t)sg*4);     // qi for it+1 (k=0)
  float4 ggC = *(const float4*)(g_arr  + (size_t)sg*4);    // gg for it=0
  float4 ggN = ggC;                                        // gg for it+1
  float4 T0 = *(const float4*)(xp + qiN.x + csel);
  float4 T1 = *(const float4*)(xp + qiN.y + csel);
  float4 T2 = *(const float4*)(xp + qiN.z + csel);
  float4 T3 = *(const float4*)(xp + qiN.w + csel);

  for (int it = 0; it < 72; it++) {
    int buf = it & 1;
    // ---- A frags for THIS iteration (L2-hot, consumed at loop end) ----
    uint4 aH[4], aL[4];
    #pragma unroll
    for (int mi = 0; mi < 4; mi++) {
      aH[mi] = *(const uint4*)(ah[mi] + it*32);
      aL[mi] = *(const uint4*)(al[mi] + it*32);
    }
    // ---- prefetch: idx/g for it+2, taps for it+1 ----
    int it2 = (it + 2 < 72) ? it + 2 : 71;
    int k2 = it2 >> 3;
    int4   qi2 = *(const int4*)(idx_arr + (size_t)(k2*NS + sg)*4);
    float4 gg2 = *(const float4*)(g_arr  + (size_t)(k2*NS + sg)*4);
    int it1 = (it + 1 < 72) ? it + 1 : 71;
    int c1 = (it1 & 7) * 32 + csel;
    float4 U0 = *(const float4*)(xp + qiN.x + c1);
    float4 U1 = *(const float4*)(xp + qiN.y + c1);
    float4 U2 = *(const float4*)(xp + qiN.z + c1);
    float4 U3 = *(const float4*)(xp + qiN.w + c1);

    // ---- build B(it) from current taps ----
    float4 v;
    v.x = ggC.x*T0.x + ggC.y*T1.x + ggC.z*T2.x + ggC.w*T3.x;
    v.y = ggC.x*T0.y + ggC.y*T1.y + ggC.z*T2.y + ggC.w*T3.y;
    v.z = ggC.x*T0.z + ggC.y*T1.z + ggC.z*T2.z + ggC.w*T3.z;
    v.w = ggC.x*T0.w + ggC.y*T1.w + ggC.z*T2.w + ggC.w*T3.w;
    u16 hb0, hb1, hb2, hb3, lb0, lb1, lb2, lb3;
    split16(v.x, hb0, lb0); split16(v.y, hb1, lb1);
    split16(v.z, hb2, lb2); split16(v.w, hb3, lb3);
    uint2 ph, pl;
    ph.x = (u32)hb0 | ((u32)hb1 << 16); ph.y = (u32)hb2 | ((u32)hb3 << 16);
    pl.x = (u32)lb0 | ((u32)lb1 << 16); pl.y = (u32)lb2 | ((u32)lb3 << 16);
    *(uint2*)(&Bh[buf][s_l*40 + csel]) = ph;
    *(uint2*)(&Bl[buf][s_l*40 + csel]) = pl;

    sync_lds();   // lgkmcnt(0)+s_barrier only; prefetches stay outstanding

    f16x8 bh = *(const f16x8*)(&Bh[buf][(nw*16 + l16)*40 + quad*8]);
    f16x8 bl = *(const f16x8*)(&Bl[buf][(nw*16 + l16)*40 + quad*8]);
    #pragma unroll
    for (int mi = 0; mi < 4; mi++) {
      f16x8 fh = __builtin_bit_cast(f16x8, aH[mi]);
      f16x8 fl = __builtin_bit_cast(f16x8, aL[mi]);
      acc[mi] = __builtin_amdgcn_mfma_f32_16x16x32_f16(fh, bh, acc[mi], 0, 0, 0);
      acc[mi] = __builtin_amdgcn_mfma_f32_16x16x32_f16(fh, bl, acc[mi], 0, 0, 0);
      acc[mi] = __builtin_amdgcn_mfma_f32_16x16x32_f16(fl, bh, acc[mi], 0, 0, 0);
    }
    // ---- shift pipeline ----
    T0 = U0; T1 = U1; T2 = U2; T3 = U3;
    ggC = ggN; ggN = gg2; qiN = qi2;
  }

  // ---- epilogue ----
  int hw = hw0 + nw*16 + l16;
  #pragma unroll
  for (int mi = 0; mi < 4; mi++) {
    #pragma unroll
    for (int rr = 0; rr < 4; rr++) {
      int o = o0 + mw*64 + mi*16 + quad*4 + rr;
      out[(size_t)(n*OC + o)*HW + hw] = acc[mi][rr];
    }
  }
}

extern "C" void kernel_launch(void* const* d_in, const int* in_sizes, int n_in,
                              void* d_out, int out_size, void* d_ws, size_t ws_size,
                              hipStream_t stream) {
  const float* x      = (const float*)d_in[0];
  const float* w_p    = (const float*)d_in[1];
  const float* b_p    = (const float*)d_in[2];
  const float* w_ad   = (const float*)d_in[3];
  const float* b_ad   = (const float*)d_in[4];
  const float* w_conv = (const float*)d_in[5];
  float* out = (float*)d_out;

  char* ws = (char*)d_ws;
  float* partial = (float*)(ws + PARTIAL_OFF);
  float* off_buf = (float*)(ws + OFFBUF_OFF);
  float* ad2_buf = (float*)(ws + AD2_OFF);
  float* xp      = (float*)(ws + XP_OFF);
  u16*   A_hi    = (u16*)  (ws + AHI_OFF);
  u16*   A_lo    = (u16*)  (ws + ALO_OFF);
  int*   idx_arr = (int*)  (ws + IDX_OFF);
  float* g_arr   = (float*)(ws + G_OFF);

  // zero padded NHWC buffer (borders must be 0; ws is poisoned each call)
  hipMemsetAsync(xp, 0, (size_t)NB*HP*HP*C*sizeof(float), stream);

  conv_small  <<<576,  256, 0, stream>>>(x, w_p, w_ad, partial);
  reduce_small<<<1512, 256, 0, stream>>>(partial, b_p, b_ad, off_buf, ad2_buf);
  pad_pack    <<<1152, 256, 0, stream>>>(x, xp);
  pack_A      <<<2304, 256, 0, stream>>>(w_conv, A_hi, A_lo);
  make_taps   <<<648,  256, 0, stream>>>(off_buf, ad2_buf, idx_arr, g_arr);
  gemm_def    <<<1152, 256, 0, stream>>>(A_hi, A_lo, xp, idx_arr, g_arr, out);
}

// Round 5
// 403.811 us; speedup vs baseline: 1.3424x; 1.3424x over previous
//
#include <hip/hip_runtime.h>
#include <math.h>

typedef unsigned short u16;
typedef unsigned int   u32;

typedef __attribute__((ext_vector_type(8))) _Float16 f16x8;
typedef __attribute__((ext_vector_type(4))) float    f32x4;

// ---------- constants ----------
#define NB   2
#define C    256
#define H    96
#define W    96
#define HW   (H*W)          // 9216
#define HP   98
#define OC   256
#define KDIM (9*C)          // 2304
#define NS   (NB*HW)        // 18432 spatial columns
#define NCHUNK 8            // channel chunks in stage-A conv

// ws layout (bytes)
#define PARTIAL_OFF  0                          // 8*2*21*9216 fp32  = 12386304
#define OFFBUF_OFF   12386304                   // 2*18*9216 fp32    = 1327104
#define AD2_OFF      13713408                   // 2*3*9216 fp32     = 221184
#define XP_OFF       13934592                   // 2*98*98*256 fp32  = 19668992
#define AHI_OFF      33603584                   // 256*2304 f16      = 1179648
#define ALO_OFF      34783232                   // 256*2304 f16      = 1179648
#define IDX_OFF      35962880                   // 9*18432*4 int     = 2654208
#define G_OFF        38617088                   // 9*18432*4 fp32    = 2654208
#define WT_OFF       41271296                   // 8*32*21*12 fp32   = 258048
// end 41529344 — under round-1-proven 42643456

__device__ __forceinline__ u16 h2u(_Float16 h) {
  return __builtin_bit_cast(unsigned short, h);
}
__device__ __forceinline__ void split16(float v, u16& hi, u16& lo) {
  _Float16 h = (_Float16)v;        // v_cvt_f16_f32, RNE
  float r = v - (float)h;          // exact residual
  _Float16 l = (_Float16)r;
  hi = h2u(h); lo = h2u(l);
}
// LDS-only barrier: waits lgkmcnt(0) but does NOT drain vmcnt — global
// prefetches stay in flight across the barrier (CK block_sync_lds pattern).
__device__ __forceinline__ void sync_lds() {
  asm volatile("s_waitcnt lgkmcnt(0)\n\ts_barrier" ::: "memory");
}

// ---------- pack weights transposed+padded for block-uniform conv reads ----------
// wT[chunk8][cc32][ch21][12]: taps 0..8 + 3 pad (aligned float4 groups)
__global__ __launch_bounds__(256) void pack_wT(
    const float* __restrict__ w_p, const float* __restrict__ w_ad,
    float* __restrict__ wT) {
  int g = blockIdx.x * 256 + threadIdx.x;    // < 8*32*21 = 5376
  if (g >= 8*32*21) return;
  int ch = g % 21; int r = g / 21; int cc = r & 31; int chunk = r >> 5;
  int gc = chunk*32 + cc;
  const float* src = (ch < 18) ? (w_p + ((size_t)ch*C + gc)*9)
                               : (w_ad + ((size_t)(ch-18)*C + gc)*9);
  float* dst = wT + (size_t)g*12;
  #pragma unroll
  for (int t = 0; t < 9; t++) dst[t] = src[t];
  dst[9] = 0.f; dst[10] = 0.f; dst[11] = 0.f;
}

// ---------- stage A: 21-ch 3x3 conv over 256c, fp32 ----------
// grid 288 = n(2) * tile(18 of 16h x 32w) * chunk(8); block 256, 2 px/thread.
// Weights via wT: block-uniform float4 loads (scalarizable). Accumulation order
// (cc ascending, taps di,dj ascending, fmaf chain) is BIT-IDENTICAL to the
// passing round-3/4 kernels — offsets unchanged, no floor-flip risk.
__global__ __launch_bounds__(256) void conv_small(
    const float* __restrict__ x, const float* __restrict__ wT,
    float* __restrict__ partial) {
  int bx = blockIdx.x;
  int chunk = bx & 7;
  int r  = bx >> 3;              // 0..35
  int tile = r % 18; int n = r / 18;
  int h0 = (tile / 3) * 16, w0 = (tile % 3) * 32;
  int tid = threadIdx.x;
  int row = tid >> 4, wg = tid & 15;
  int h = h0 + row, w = w0 + wg*2;

  float acc[21][2];
  #pragma unroll
  for (int ch = 0; ch < 21; ch++) { acc[ch][0] = 0.f; acc[ch][1] = 0.f; }

  const float* xn = x + (size_t)(n*C + chunk*32) * HW;
  const float* wbase = wT + (size_t)chunk * 32*21*12;
  for (int cc = 0; cc < 32; cc++) {
    const float* xc = xn + cc * HW;
    float xr[3][4];
    #pragma unroll
    for (int di = 0; di < 3; di++) {
      int hg = h + di - 1;
      bool hok = ((unsigned)hg < 96u);
      #pragma unroll
      for (int jj = 0; jj < 4; jj++) {
        int wgl = w + jj - 1;
        bool ok = hok && ((unsigned)wgl < 96u);
        xr[di][jj] = ok ? xc[hg*W + wgl] : 0.f;
      }
    }
    const float* wc = wbase + cc * 21*12;
    #pragma unroll
    for (int ch = 0; ch < 21; ch++) {
      const float* wv = wc + ch*12;            // uniform across block
      float4 wa = *(const float4*)(wv);
      float4 wb = *(const float4*)(wv + 4);
      float  w8 = wv[8];
      float wt[9] = {wa.x, wa.y, wa.z, wa.w, wb.x, wb.y, wb.z, wb.w, w8};
      #pragma unroll
      for (int di = 0; di < 3; di++)
        #pragma unroll
        for (int dj = 0; dj < 3; dj++) {
          float wgt = wt[di*3 + dj];
          acc[ch][0] = fmaf(xr[di][dj],     wgt, acc[ch][0]);
          acc[ch][1] = fmaf(xr[di][dj + 1], wgt, acc[ch][1]);
        }
    }
  }
  #pragma unroll
  for (int ch = 0; ch < 21; ch++) {
    int off = ((chunk*2 + n)*21 + ch)*HW + h*W + w;
    *(float2*)(partial + off) = make_float2(acc[ch][0], acc[ch][1]);
  }
}

// ---------- reduce partials, add bias, sigmoid for ad ----------
__global__ __launch_bounds__(256) void reduce_small(
    const float* __restrict__ partial, const float* __restrict__ b_p,
    const float* __restrict__ b_ad, float* __restrict__ off_buf,
    float* __restrict__ ad2_buf) {
  int e = blockIdx.x * 256 + threadIdx.x;
  if (e >= NB*21*HW) return;
  int n  = e / (21*HW);
  int r  = e % (21*HW);
  int ch = r / HW;
  int hw = r % HW;
  float s = 0.f;
  #pragma unroll
  for (int chunk = 0; chunk < NCHUNK; chunk++)
    s += partial[((chunk*2 + n)*21 + ch)*HW + hw];
  if (ch < 18) {
    off_buf[(n*18 + ch)*HW + hw] = s + b_p[ch];
  } else {
    float z = s + b_ad[ch - 18];
    ad2_buf[(n*3 + (ch-18))*HW + hw] = 2.0f / (1.0f + expf(z));   // (1-sigmoid)*DIL
  }
}

// ---------- NCHW fp32 -> padded NHWC fp32 (borders pre-zeroed by memset) ----------
__global__ __launch_bounds__(256) void pad_pack(
    const float* __restrict__ x, float* __restrict__ xp) {
  __shared__ float ts[64][65];
  int bx = blockIdx.x;
  int n = bx / 576; int r = bx % 576;
  int cb = r / 144; int hwb = r % 144;
  int c0 = cb * 64, hw0 = hwb * 64;
  int tid = threadIdx.x;
  int ii = tid & 63; int cl4 = tid >> 6;
  #pragma unroll
  for (int r2 = 0; r2 < 16; r2++) {
    int c_l = cl4*16 + r2;
    ts[c_l][ii] = x[(size_t)(n*C + c0 + c_l)*HW + hw0 + ii];
  }
  __syncthreads();
  int hw = hw0 + ii;
  int h = hw / W, w = hw % W;
  float* dst = xp + ((size_t)(n*HP + h + 1)*HP + (w + 1))*C + c0 + cl4*16;
  #pragma unroll
  for (int q = 0; q < 4; q++) {
    *(float4*)(dst + q*4) = make_float4(ts[cl4*16 + q*4 + 0][ii], ts[cl4*16 + q*4 + 1][ii],
                                        ts[cl4*16 + q*4 + 2][ii], ts[cl4*16 + q*4 + 3][ii]);
  }
}

// ---------- repack + split w_conv [o][c][k] -> A_hi/A_lo [o][k*256+c] f16 ----------
__global__ __launch_bounds__(256) void pack_A(
    const float* __restrict__ w_conv, u16* __restrict__ A_hi, u16* __restrict__ A_lo) {
  int e = blockIdx.x * 256 + threadIdx.x;      // < 256*2304
  int o = e / KDIM; int r = e % KDIM; int k = r >> 8; int c = r & 255;
  float a = w_conv[(o*C + c)*9 + k];
  u16 hi, lo; split16(a, hi, lo);
  A_hi[e] = hi; A_lo[e] = lo;
}

// ---------- bilinear taps: 4 indices + 4 weights per (s, k) ----------
__global__ __launch_bounds__(256) void make_taps(
    const float* __restrict__ off_buf, const float* __restrict__ ad2_buf,
    int* __restrict__ idx_arr, float* __restrict__ g_arr) {
  int e = blockIdx.x * 256 + threadIdx.x;      // < 9*18432
  int k = e / NS; int s = e % NS;
  int n = s / HW; int hw = s % HW;
  int h = hw / W, w = hw % W;
  float ri = (float)(k / 3) - 1.0f, rj = (float)(k % 3) - 1.0f;
  float offx = off_buf[(n*18 + k)*HW + hw];
  float offy = off_buf[(n*18 + k + 9)*HW + hw];
  float a2   = ad2_buf[(n*3 + (k % 3))*HW + hw];
  float px = (float)(h + 1) + ri + offx + a2 * ri;
  float py = (float)(w + 1) + rj + offy + a2 * rj;
  float fx = floorf(px), fy = floorf(py);
  int qltx = min(max((int)fx, 0), 97);
  int qlty = min(max((int)fy, 0), 97);
  int qrbx = min(max((int)fx + 1, 0), 97);
  int qrby = min(max((int)fy + 1, 0), 97);
  bool mx = (px < 1.0f) || (px > 96.0f);
  bool my = (py < 1.0f) || (py > 96.0f);
  float pxm = mx ? fx : px;
  float pym = my ? fy : py;
  pxm = fminf(fmaxf(pxm, 0.f), 97.f);
  pym = fminf(fmaxf(pym, 0.f), 97.f);
  float glx = 1.0f + ((float)qltx - pxm);
  float grx = 1.0f - ((float)qrbx - pxm);
  float gly = 1.0f + ((float)qlty - pym);
  float gry = 1.0f - ((float)qrby - pym);
  int base = n * HP * HP * C;
  int4 qi;
  qi.x = base + (qltx*HP + qlty)*C;   // lt
  qi.y = base + (qrbx*HP + qrby)*C;   // rb
  qi.z = base + (qltx*HP + qrby)*C;   // lb
  qi.w = base + (qrbx*HP + qlty)*C;   // rt
  float4 gg = make_float4(glx*gly, grx*gry, glx*gry, grx*gly);
  *(int4*)(idx_arr + (size_t)e*4) = qi;
  *(float4*)(g_arr  + (size_t)e*4) = gg;
}

// ---------- fused gather + split-f16 MFMA GEMM (round-3 skeleton + split-K) ----------
// C[o,s] = sum_kc A[o,kc]*B[kc,s]; 3-term split-f16.
// grid 1152 = sb(288: 64 s) * kh(2: K-half) * mo(2: 128 o); block 256
// (4 waves: mw x 64 o, nw x 32 s). Single-buffered LDS, two lgkm-only barriers
// per iter (no vmcnt drain). Epilogue: atomicAdd (out pre-zeroed).
__global__ void gemm_def(
    const u16* __restrict__ A_hi, const u16* __restrict__ A_lo,
    const float* __restrict__ xp,
    const int* __restrict__ idx_arr, const float* __restrict__ g_arr,
    float* __restrict__ out) {
  __shared__ u16 Ah[128*40];
  __shared__ u16 Al[128*40];
  __shared__ u16 Bh[64*40];
  __shared__ u16 Bl[64*40];
  int bx = blockIdx.x;
  int mo = bx & 1; int kh = (bx >> 1) & 1; int sb = bx >> 2;
  int o0 = mo * 128; int s0 = sb * 64;
  int n = s0 / HW; int hw0 = s0 % HW;
  int tid = threadIdx.x;
  int wave = tid >> 6, lane = tid & 63;
  int l16 = lane & 15, quad = lane >> 4;
  int mw = wave >> 1, nw = wave & 1;

  f32x4 acc[4][2];
  f32x4 z4 = {0.f, 0.f, 0.f, 0.f};
  #pragma unroll
  for (int i = 0; i < 4; i++)
    { acc[i][0] = z4; acc[i][1] = z4; }

  int arow = tid >> 1; int acs = (tid & 1) * 16;
  const u16* agh = A_hi + (size_t)(o0 + arow) * KDIM + acs;
  const u16* agl = A_lo + (size_t)(o0 + arow) * KDIM + acs;
  int s_l = tid >> 2; int cs = (tid & 3) * 8;
  int sg = s0 + s_l;

  for (int it = 0; it < 36; it++) {
    int itg = kh*36 + it;
    int kbase = itg * 32;
    int k   = itg >> 3;
    int c0k = (itg & 7) * 32;
    // global loads issued early (pinned before the barrier)
    uint4 a0h = *(const uint4*)(agh + kbase);
    uint4 a1h = *(const uint4*)(agh + kbase + 8);
    uint4 a0l = *(const uint4*)(agl + kbase);
    uint4 a1l = *(const uint4*)(agl + kbase + 8);
    int4   qi = *(const int4*)(idx_arr + (size_t)(k*NS + sg)*4);
    float4 gg = *(const float4*)(g_arr  + (size_t)(k*NS + sg)*4);
    const float* p0 = xp + qi.x + c0k + cs;
    const float* p1 = xp + qi.y + c0k + cs;
    const float* p2 = xp + qi.z + c0k + cs;
    const float* p3 = xp + qi.w + c0k + cs;
    float4 t0a = *(const float4*)(p0), t0b = *(const float4*)(p0 + 4);
    float4 t1a = *(const float4*)(p1), t1b = *(const float4*)(p1 + 4);
    float4 t2a = *(const float4*)(p2), t2b = *(const float4*)(p2 + 4);
    float4 t3a = *(const float4*)(p3), t3b = *(const float4*)(p3 + 4);
    float v[8];
    v[0] = gg.x*t0a.x + gg.y*t1a.x + gg.z*t2a.x + gg.w*t3a.x;
    v[1] = gg.x*t0a.y + gg.y*t1a.y + gg.z*t2a.y + gg.w*t3a.y;
    v[2] = gg.x*t0a.z + gg.y*t1a.z + gg.z*t2a.z + gg.w*t3a.z;
    v[3] = gg.x*t0a.w + gg.y*t1a.w + gg.z*t2a.w + gg.w*t3a.w;
    v[4] = gg.x*t0b.x + gg.y*t1b.x + gg.z*t2b.x + gg.w*t3b.x;
    v[5] = gg.x*t0b.y + gg.y*t1b.y + gg.z*t2b.y + gg.w*t3b.y;
    v[6] = gg.x*t0b.z + gg.y*t1b.z + gg.z*t2b.z + gg.w*t3b.z;
    v[7] = gg.x*t0b.w + gg.y*t1b.w + gg.z*t2b.w + gg.w*t3b.w;
    u16 hb[8], lb[8];
    #pragma unroll
    for (int j = 0; j < 8; j++) split16(v[j], hb[j], lb[j]);
    sync_lds();                    // prior frag ds_reads done; no vmcnt drain
    *(uint4*)(Ah + arow*40 + acs)     = a0h;
    *(uint4*)(Ah + arow*40 + acs + 8) = a1h;
    *(uint4*)(Al + arow*40 + acs)     = a0l;
    *(uint4*)(Al + arow*40 + acs + 8) = a1l;
    uint4 bph, bpl;
    bph.x = (u32)hb[0] | ((u32)hb[1] << 16); bph.y = (u32)hb[2] | ((u32)hb[3] << 16);
    bph.z = (u32)hb[4] | ((u32)hb[5] << 16); bph.w = (u32)hb[6] | ((u32)hb[7] << 16);
    bpl.x = (u32)lb[0] | ((u32)lb[1] << 16); bpl.y = (u32)lb[2] | ((u32)lb[3] << 16);
    bpl.z = (u32)lb[4] | ((u32)lb[5] << 16); bpl.w = (u32)lb[6] | ((u32)lb[7] << 16);
    *(uint4*)(Bh + s_l*40 + cs) = bph;
    *(uint4*)(Bl + s_l*40 + cs) = bpl;
    sync_lds();                    // LDS writes visible; no vmcnt drain
    f16x8 afh[4], afl[4], bfh[2], bfl[2];
    #pragma unroll
    for (int mi = 0; mi < 4; mi++) {
      int rr = (mw*64 + mi*16 + l16)*40 + quad*8;
      afh[mi] = *(const f16x8*)(Ah + rr);
      afl[mi] = *(const f16x8*)(Al + rr);
    }
    #pragma unroll
    for (int ni = 0; ni < 2; ni++) {
      int rr = (nw*32 + ni*16 + l16)*40 + quad*8;
      bfh[ni] = *(const f16x8*)(Bh + rr);
      bfl[ni] = *(const f16x8*)(Bl + rr);
    }
    #pragma unroll
    for (int mi = 0; mi < 4; mi++)
      #pragma unroll
      for (int ni = 0; ni < 2; ni++) {
        acc[mi][ni] = __builtin_amdgcn_mfma_f32_16x16x32_f16(afh[mi], bfh[ni], acc[mi][ni], 0, 0, 0);
        acc[mi][ni] = __builtin_amdgcn_mfma_f32_16x16x32_f16(afh[mi], bfl[ni], acc[mi][ni], 0, 0, 0);
        acc[mi][ni] = __builtin_amdgcn_mfma_f32_16x16x32_f16(afl[mi], bfh[ni], acc[mi][ni], 0, 0, 0);
      }
  }
  #pragma unroll
  for (int mi = 0; mi < 4; mi++)
    #pragma unroll
    for (int ni = 0; ni < 2; ni++) {
      int hw = hw0 + nw*32 + ni*16 + l16;
      #pragma unroll
      for (int rr = 0; rr < 4; rr++) {
        int o = o0 + mw*64 + mi*16 + quad*4 + rr;
        atomicAdd(&out[(size_t)(n*OC + o)*HW + hw], acc[mi][ni][rr]);
      }
    }
}

extern "C" void kernel_launch(void* const* d_in, const int* in_sizes, int n_in,
                              void* d_out, int out_size, void* d_ws, size_t ws_size,
                              hipStream_t stream) {
  const float* x      = (const float*)d_in[0];
  const float* w_p    = (const float*)d_in[1];
  const float* b_p    = (const float*)d_in[2];
  const float* b_ad   = (const float*)d_in[4];
  const float* w_ad   = (const float*)d_in[3];
  const float* w_conv = (const float*)d_in[5];
  float* out = (float*)d_out;

  char* ws = (char*)d_ws;
  float* partial = (float*)(ws + PARTIAL_OFF);
  float* off_buf = (float*)(ws + OFFBUF_OFF);
  float* ad2_buf = (float*)(ws + AD2_OFF);
  float* xp      = (float*)(ws + XP_OFF);
  u16*   A_hi    = (u16*)  (ws + AHI_OFF);
  u16*   A_lo    = (u16*)  (ws + ALO_OFF);
  int*   idx_arr = (int*)  (ws + IDX_OFF);
  float* g_arr   = (float*)(ws + G_OFF);
  float* wT      = (float*)(ws + WT_OFF);

  // zero padded NHWC buffer + output (split-K accumulates via atomics)
  hipMemsetAsync(xp, 0, (size_t)NB*HP*HP*C*sizeof(float), stream);
  hipMemsetAsync(out, 0, (size_t)out_size*sizeof(float), stream);

  pack_wT     <<<21,   256, 0, stream>>>(w_p, w_ad, wT);
  conv_small  <<<288,  256, 0, stream>>>(x, wT, partial);
  reduce_small<<<1512, 256, 0, stream>>>(partial, b_p, b_ad, off_buf, ad2_buf);
  pad_pack    <<<1152, 256, 0, stream>>>(x, xp);
  pack_A      <<<2304, 256, 0, stream>>>(w_conv, A_hi, A_lo);
  make_taps   <<<648,  256, 0, stream>>>(off_buf, ad2_buf, idx_arr, g_arr);
  gemm_def    <<<1152, 256, 0, stream>>>(A_hi, A_lo, xp, idx_arr, g_arr, out);
}

// Round 7
// 340.417 us; speedup vs baseline: 1.5924x; 1.1862x over previous
//
#include <hip/hip_runtime.h>
#include <math.h>

typedef unsigned short u16;
typedef unsigned int   u32;

typedef __attribute__((ext_vector_type(8))) _Float16 f16x8;
typedef __attribute__((ext_vector_type(4))) float    f32x4;

// ---------- constants ----------
#define NB   2
#define C    256
#define H    96
#define W    96
#define HW   (H*W)          // 9216
#define HP   98
#define OC   256
#define KDIM (9*C)          // 2304
#define NS   (NB*HW)        // 18432 spatial columns
#define NCHUNK 8            // channel chunks in stage-A conv

// ws layout (bytes)
#define PARTIAL_OFF  0                          // 8*2*21*9216 fp32  = 12386304
#define OFFBUF_OFF   12386304                   // 2*18*9216 fp32    = 1327104
#define AD2_OFF      13713408                   // 2*3*9216 fp32     = 221184
#define XP_OFF       13934592                   // 2*98*98*256 fp32  = 19668992
#define AHI_OFF      33603584                   // 256*2304 f16      = 1179648
#define ALO_OFF      34783232                   // 256*2304 f16      = 1179648
#define IDX_OFF      35962880                   // 9*18432*4 int     = 2654208
#define G_OFF        38617088                   // 9*18432*4 fp32    = 2654208
#define WT_OFF       41271296                   // 8*32*21*12 fp32   = 258048

__device__ __forceinline__ u16 h2u(_Float16 h) {
  return __builtin_bit_cast(unsigned short, h);
}
__device__ __forceinline__ void split16(float v, u16& hi, u16& lo) {
  _Float16 h = (_Float16)v;        // v_cvt_f16_f32, RNE
  float r = v - (float)h;          // exact residual
  _Float16 l = (_Float16)r;
  hi = h2u(h); lo = h2u(l);
}
// LDS-only barrier: waits lgkmcnt(0) but does NOT drain vmcnt — global
// prefetches stay in flight across the barrier (CK block_sync_lds pattern).
__device__ __forceinline__ void sync_lds() {
  asm volatile("s_waitcnt lgkmcnt(0)\n\ts_barrier" ::: "memory");
}

// ---------- pack weights transposed+padded: wT[chunk8][cc32][ch21][12] ----------
__global__ __launch_bounds__(256) void pack_wT(
    const float* __restrict__ w_p, const float* __restrict__ w_ad,
    float* __restrict__ wT) {
  int g = blockIdx.x * 256 + threadIdx.x;    // < 8*32*21 = 5376
  if (g >= 8*32*21) return;
  int ch = g % 21; int r = g / 21; int cc = r & 31; int chunk = r >> 5;
  int gc = chunk*32 + cc;
  const float* src = (ch < 18) ? (w_p + ((size_t)ch*C + gc)*9)
                               : (w_ad + ((size_t)(ch-18)*C + gc)*9);
  float* dst = wT + (size_t)g*12;
  #pragma unroll
  for (int t = 0; t < 9; t++) dst[t] = src[t];
  dst[9] = 0.f; dst[10] = 0.f; dst[11] = 0.f;
}

// ---------- stage A conv: 21ch 3x3 over 256c, fp32 ----------
// grid 1152 = n(2)*tile(36 of 16x16)*chunk(8)*chgroup(2); block 256, 1 px/thread.
// Per-output accumulation order (cc ascending, taps t ascending, fmaf chain) is
// BIT-IDENTICAL to rounds 3-5 — offsets unchanged, no floor-flip risk.
__global__ __launch_bounds__(256) void conv_small(
    const float* __restrict__ x, const float* __restrict__ wT,
    float* __restrict__ partial) {
  int bx = blockIdx.x;
  int cg = bx & 1; int chunk = (bx >> 1) & 7; int r = bx >> 4;
  int tile = r % 36; int n = r / 36;
  int h0 = (tile / 6) * 16, w0 = (tile % 6) * 16;
  int tid = threadIdx.x;
  int row = tid >> 4, col = tid & 15;
  int h = h0 + row, w = w0 + col;
  int chB = cg * 11; int chN = cg ? 10 : 11;

  float acc[11];
  #pragma unroll
  for (int i = 0; i < 11; i++) acc[i] = 0.f;

  const float* xn = x + (size_t)(n*C + chunk*32) * HW;
  const float* wbase = wT + (size_t)chunk * 32*21*12 + chB*12;
  for (int cc = 0; cc < 32; cc++) {
    const float* xc = xn + cc * HW;
    float xr[9];
    #pragma unroll
    for (int di = 0; di < 3; di++) {
      int hg = h + di - 1;
      bool hok = ((unsigned)hg < 96u);
      #pragma unroll
      for (int dj = 0; dj < 3; dj++) {
        int wg = w + dj - 1;
        bool ok = hok && ((unsigned)wg < 96u);
        xr[di*3+dj] = ok ? xc[hg*W + wg] : 0.f;
      }
    }
    const float* wc = wbase + cc * 21*12;
    #pragma unroll
    for (int chl = 0; chl < 11; chl++) {
      if (chl < chN) {                         // block-uniform bound
        const float* wv = wc + chl*12;
        float4 wa = *(const float4*)(wv);
        float4 wb = *(const float4*)(wv + 4);
        float  w8 = wv[8];
        acc[chl] = fmaf(xr[0], wa.x, acc[chl]);
        acc[chl] = fmaf(xr[1], wa.y, acc[chl]);
        acc[chl] = fmaf(xr[2], wa.z, acc[chl]);
        acc[chl] = fmaf(xr[3], wa.w, acc[chl]);
        acc[chl] = fmaf(xr[4], wb.x, acc[chl]);
        acc[chl] = fmaf(xr[5], wb.y, acc[chl]);
        acc[chl] = fmaf(xr[6], wb.z, acc[chl]);
        acc[chl] = fmaf(xr[7], wb.w, acc[chl]);
        acc[chl] = fmaf(xr[8], w8,   acc[chl]);
      }
    }
  }
  #pragma unroll
  for (int chl = 0; chl < 11; chl++) {
    if (chl < chN)
      partial[((chunk*2 + n)*21 + chB + chl)*HW + h*W + w] = acc[chl];
  }
}

// ---------- reduce partials, add bias, sigmoid for ad ----------
__global__ __launch_bounds__(256) void reduce_small(
    const float* __restrict__ partial, const float* __restrict__ b_p,
    const float* __restrict__ b_ad, float* __restrict__ off_buf,
    float* __restrict__ ad2_buf) {
  int e = blockIdx.x * 256 + threadIdx.x;
  if (e >= NB*21*HW) return;
  int n  = e / (21*HW);
  int r  = e % (21*HW);
  int ch = r / HW;
  int hw = r % HW;
  float s = 0.f;
  #pragma unroll
  for (int chunk = 0; chunk < NCHUNK; chunk++)
    s += partial[((chunk*2 + n)*21 + ch)*HW + hw];
  if (ch < 18) {
    off_buf[(n*18 + ch)*HW + hw] = s + b_p[ch];
  } else {
    float z = s + b_ad[ch - 18];
    ad2_buf[(n*3 + (ch-18))*HW + hw] = 2.0f / (1.0f + expf(z));   // (1-sigmoid)*DIL
  }
}

// ---------- NCHW fp32 -> padded NHWC fp32 (borders pre-zeroed by memset) ----------
__global__ __launch_bounds__(256) void pad_pack(
    const float* __restrict__ x, float* __restrict__ xp) {
  __shared__ float ts[64][65];
  int bx = blockIdx.x;
  int n = bx / 576; int r = bx % 576;
  int cb = r / 144; int hwb = r % 144;
  int c0 = cb * 64, hw0 = hwb * 64;
  int tid = threadIdx.x;
  int ii = tid & 63; int cl4 = tid >> 6;
  #pragma unroll
  for (int r2 = 0; r2 < 16; r2++) {
    int c_l = cl4*16 + r2;
    ts[c_l][ii] = x[(size_t)(n*C + c0 + c_l)*HW + hw0 + ii];
  }
  __syncthreads();
  int hw = hw0 + ii;
  int h = hw / W, w = hw % W;
  float* dst = xp + ((size_t)(n*HP + h + 1)*HP + (w + 1))*C + c0 + cl4*16;
  #pragma unroll
  for (int q = 0; q < 4; q++) {
    *(float4*)(dst + q*4) = make_float4(ts[cl4*16 + q*4 + 0][ii], ts[cl4*16 + q*4 + 1][ii],
                                        ts[cl4*16 + q*4 + 2][ii], ts[cl4*16 + q*4 + 3][ii]);
  }
}

// ---------- repack + split w_conv [o][c][k] -> A_hi/A_lo [o][k*256+c] f16 ----------
// (round-5 row-major layout — proven)
__global__ __launch_bounds__(256) void pack_A(
    const float* __restrict__ w_conv, u16* __restrict__ A_hi, u16* __restrict__ A_lo) {
  int e = blockIdx.x * 256 + threadIdx.x;      // < 256*2304
  int o = e / KDIM; int r = e % KDIM; int k = r >> 8; int c = r & 255;
  float a = w_conv[(o*C + c)*9 + k];
  u16 hi, lo; split16(a, hi, lo);
  A_hi[e] = hi; A_lo[e] = lo;
}

// ---------- bilinear taps: 4 indices + 4 weights per (s, k) ----------
__global__ __launch_bounds__(256) void make_taps(
    const float* __restrict__ off_buf, const float* __restrict__ ad2_buf,
    int* __restrict__ idx_arr, float* __restrict__ g_arr) {
  int e = blockIdx.x * 256 + threadIdx.x;      // < 9*18432
  int k = e / NS; int s = e % NS;
  int n = s / HW; int hw = s % HW;
  int h = hw / W, w = hw % W;
  float ri = (float)(k / 3) - 1.0f, rj = (float)(k % 3) - 1.0f;
  float offx = off_buf[(n*18 + k)*HW + hw];
  float offy = off_buf[(n*18 + k + 9)*HW + hw];
  float a2   = ad2_buf[(n*3 + (k % 3))*HW + hw];
  float px = (float)(h + 1) + ri + offx + a2 * ri;
  float py = (float)(w + 1) + rj + offy + a2 * rj;
  float fx = floorf(px), fy = floorf(py);
  int qltx = min(max((int)fx, 0), 97);
  int qlty = min(max((int)fy, 0), 97);
  int qrbx = min(max((int)fx + 1, 0), 97);
  int qrby = min(max((int)fy + 1, 0), 97);
  bool mx = (px < 1.0f) || (px > 96.0f);
  bool my = (py < 1.0f) || (py > 96.0f);
  float pxm = mx ? fx : px;
  float pym = my ? fy : py;
  pxm = fminf(fmaxf(pxm, 0.f), 97.f);
  pym = fminf(fmaxf(pym, 0.f), 97.f);
  float glx = 1.0f + ((float)qltx - pxm);
  float grx = 1.0f - ((float)qrbx - pxm);
  float gly = 1.0f + ((float)qlty - pym);
  float gry = 1.0f - ((float)qrby - pym);
  int base = n * HP * HP * C;
  int4 qi;
  qi.x = base + (qltx*HP + qlty)*C;   // lt
  qi.y = base + (qrbx*HP + qrby)*C;   // rb
  qi.z = base + (qltx*HP + qrby)*C;   // lb
  qi.w = base + (qrbx*HP + qlty)*C;   // rt
  float4 gg = make_float4(glx*gly, grx*gry, glx*gry, grx*gly);
  *(int4*)(idx_arr + (size_t)e*4) = qi;
  *(float4*)(g_arr  + (size_t)e*4) = gg;
}

// ---------- fused gather + split-f16 MFMA GEMM (round-5 body, PROVEN) ----------
// C[o,s] = sum_kc A[o,kc]*B[kc,s]; 3-term split-f16.
// grid 1152 = sb(288: 64 s) * kh(2: K-half) * mo(2: 128 o); block 256
// (4 waves: mw x 64 o, nw x 32 s). Single-buffered LDS, two lgkm-only barriers
// per iter (no vmcnt drain). Epilogue: atomicAdd (out pre-zeroed).
__global__ void gemm_def(
    const u16* __restrict__ A_hi, const u16* __restrict__ A_lo,
    const float* __restrict__ xp,
    const int* __restrict__ idx_arr, const float* __restrict__ g_arr,
    float* __restrict__ out) {
  __shared__ u16 Ah[128*40];
  __shared__ u16 Al[128*40];
  __shared__ u16 Bh[64*40];
  __shared__ u16 Bl[64*40];
  int bx = blockIdx.x;
  int mo = bx & 1; int kh = (bx >> 1) & 1; int sb = bx >> 2;
  int o0 = mo * 128; int s0 = sb * 64;
  int n = s0 / HW; int hw0 = s0 % HW;
  int tid = threadIdx.x;
  int wave = tid >> 6, lane = tid & 63;
  int l16 = lane & 15, quad = lane >> 4;
  int mw = wave >> 1, nw = wave & 1;

  f32x4 acc[4][2];
  f32x4 z4 = {0.f, 0.f, 0.f, 0.f};
  #pragma unroll
  for (int i = 0; i < 4; i++)
    { acc[i][0] = z4; acc[i][1] = z4; }

  int arow = tid >> 1; int acs = (tid & 1) * 16;
  const u16* agh = A_hi + (size_t)(o0 + arow) * KDIM + acs;
  const u16* agl = A_lo + (size_t)(o0 + arow) * KDIM + acs;
  int s_l = tid >> 2; int cs = (tid & 3) * 8;
  int sg = s0 + s_l;

  for (int it = 0; it < 36; it++) {
    int itg = kh*36 + it;
    int kbase = itg * 32;
    int k   = itg >> 3;
    int c0k = (itg & 7) * 32;
    // global loads issued early (pinned before the barrier)
    uint4 a0h = *(const uint4*)(agh + kbase);
    uint4 a1h = *(const uint4*)(agh + kbase + 8);
    uint4 a0l = *(const uint4*)(agl + kbase);
    uint4 a1l = *(const uint4*)(agl + kbase + 8);
    int4   qi = *(const int4*)(idx_arr + (size_t)(k*NS + sg)*4);
    float4 gg = *(const float4*)(g_arr  + (size_t)(k*NS + sg)*4);
    const float* p0 = xp + qi.x + c0k + cs;
    const float* p1 = xp + qi.y + c0k + cs;
    const float* p2 = xp + qi.z + c0k + cs;
    const float* p3 = xp + qi.w + c0k + cs;
    float4 t0a = *(const float4*)(p0), t0b = *(const float4*)(p0 + 4);
    float4 t1a = *(const float4*)(p1), t1b = *(const float4*)(p1 + 4);
    float4 t2a = *(const float4*)(p2), t2b = *(const float4*)(p2 + 4);
    float4 t3a = *(const float4*)(p3), t3b = *(const float4*)(p3 + 4);
    float v[8];
    v[0] = gg.x*t0a.x + gg.y*t1a.x + gg.z*t2a.x + gg.w*t3a.x;
    v[1] = gg.x*t0a.y + gg.y*t1a.y + gg.z*t2a.y + gg.w*t3a.y;
    v[2] = gg.x*t0a.z + gg.y*t1a.z + gg.z*t2a.z + gg.w*t3a.z;
    v[3] = gg.x*t0a.w + gg.y*t1a.w + gg.z*t2a.w + gg.w*t3a.w;
    v[4] = gg.x*t0b.x + gg.y*t1b.x + gg.z*t2b.x + gg.w*t3b.x;
    v[5] = gg.x*t0b.y + gg.y*t1b.y + gg.z*t2b.y + gg.w*t3b.y;
    v[6] = gg.x*t0b.z + gg.y*t1b.z + gg.z*t2b.z + gg.w*t3b.z;
    v[7] = gg.x*t0b.w + gg.y*t1b.w + gg.z*t2b.w + gg.w*t3b.w;
    u16 hb[8], lb[8];
    #pragma unroll
    for (int j = 0; j < 8; j++) split16(v[j], hb[j], lb[j]);
    sync_lds();                    // prior frag ds_reads done; no vmcnt drain
    *(uint4*)(Ah + arow*40 + acs)     = a0h;
    *(uint4*)(Ah + arow*40 + acs + 8) = a1h;
    *(uint4*)(Al + arow*40 + acs)     = a0l;
    *(uint4*)(Al + arow*40 + acs + 8) = a1l;
    uint4 bph, bpl;
    bph.x = (u32)hb[0] | ((u32)hb[1] << 16); bph.y = (u32)hb[2] | ((u32)hb[3] << 16);
    bph.z = (u32)hb[4] | ((u32)hb[5] << 16); bph.w = (u32)hb[6] | ((u32)hb[7] << 16);
    bpl.x = (u32)lb[0] | ((u32)lb[1] << 16); bpl.y = (u32)lb[2] | ((u32)lb[3] << 16);
    bpl.z = (u32)lb[4] | ((u32)lb[5] << 16); bpl.w = (u32)lb[6] | ((u32)lb[7] << 16);
    *(uint4*)(Bh + s_l*40 + cs) = bph;
    *(uint4*)(Bl + s_l*40 + cs) = bpl;
    sync_lds();                    // LDS writes visible; no vmcnt drain
    f16x8 afh[4], afl[4], bfh[2], bfl[2];
    #pragma unroll
    for (int mi = 0; mi < 4; mi++) {
      int rr = (mw*64 + mi*16 + l16)*40 + quad*8;
      afh[mi] = *(const f16x8*)(Ah + rr);
      afl[mi] = *(const f16x8*)(Al + rr);
    }
    #pragma unroll
    for (int ni = 0; ni < 2; ni++) {
      int rr = (nw*32 + ni*16 + l16)*40 + quad*8;
      bfh[ni] = *(const f16x8*)(Bh + rr);
      bfl[ni] = *(const f16x8*)(Bl + rr);
    }
    #pragma unroll
    for (int mi = 0; mi < 4; mi++)
      #pragma unroll
      for (int ni = 0; ni < 2; ni++) {
        acc[mi][ni] = __builtin_amdgcn_mfma_f32_16x16x32_f16(afh[mi], bfh[ni], acc[mi][ni], 0, 0, 0);
        acc[mi][ni] = __builtin_amdgcn_mfma_f32_16x16x32_f16(afh[mi], bfl[ni], acc[mi][ni], 0, 0, 0);
        acc[mi][ni] = __builtin_amdgcn_mfma_f32_16x16x32_f16(afl[mi], bfh[ni], acc[mi][ni], 0, 0, 0);
      }
  }
  #pragma unroll
  for (int mi = 0; mi < 4; mi++)
    #pragma unroll
    for (int ni = 0; ni < 2; ni++) {
      int hw = hw0 + nw*32 + ni*16 + l16;
      #pragma unroll
      for (int rr = 0; rr < 4; rr++) {
        int o = o0 + mw*64 + mi*16 + quad*4 + rr;
        atomicAdd(&out[(size_t)(n*OC + o)*HW + hw], acc[mi][ni][rr]);
      }
    }
}

extern "C" void kernel_launch(void* const* d_in, const int* in_sizes, int n_in,
                              void* d_out, int out_size, void* d_ws, size_t ws_size,
                              hipStream_t stream) {
  const float* x      = (const float*)d_in[0];
  const float* w_p    = (const float*)d_in[1];
  const float* b_p    = (const float*)d_in[2];
  const float* w_ad   = (const float*)d_in[3];
  const float* b_ad   = (const float*)d_in[4];
  const float* w_conv = (const float*)d_in[5];
  float* out = (float*)d_out;

  char* ws = (char*)d_ws;
  float* partial = (float*)(ws + PARTIAL_OFF);
  float* off_buf = (float*)(ws + OFFBUF_OFF);
  float* ad2_buf = (float*)(ws + AD2_OFF);
  float* xp      = (float*)(ws + XP_OFF);
  u16*   A_hi    = (u16*)  (ws + AHI_OFF);
  u16*   A_lo    = (u16*)  (ws + ALO_OFF);
  int*   idx_arr = (int*)  (ws + IDX_OFF);
  float* g_arr   = (float*)(ws + G_OFF);
  float* wT      = (float*)(ws + WT_OFF);

  hipMemsetAsync(xp, 0, (size_t)NB*HP*HP*C*sizeof(float), stream);
  hipMemsetAsync(out, 0, (size_t)out_size*sizeof(float), stream);

  pack_wT     <<<21,   256, 0, stream>>>(w_p, w_ad, wT);
  conv_small  <<<1152, 256, 0, stream>>>(x, wT, partial);
  reduce_small<<<1512, 256, 0, stream>>>(partial, b_p, b_ad, off_buf, ad2_buf);
  pad_pack    <<<1152, 256, 0, stream>>>(x, xp);
  pack_A      <<<2304, 256, 0, stream>>>(w_conv, A_hi, A_lo);
  make_taps   <<<648,  256, 0, stream>>>(off_buf, ad2_buf, idx_arr, g_arr);
  gemm_def    <<<1152, 256, 0, stream>>>(A_hi, A_lo, xp, idx_arr, g_arr, out);
}

// Round 8
// 254.003 us; speedup vs baseline: 2.1341x; 1.3402x over previous
//
#include <hip/hip_runtime.h>
#include <math.h>

typedef unsigned short u16;
typedef unsigned int   u32;

typedef __attribute__((ext_vector_type(8))) _Float16 f16x8;
typedef __attribute__((ext_vector_type(4))) float    f32x4;

// ---------- constants ----------
#define NB   2
#define C    256
#define H    96
#define W    96
#define HW   (H*W)          // 9216
#define HP   98
#define OC   256
#define KDIM (9*C)          // 2304
#define NS   (NB*HW)        // 18432 spatial columns

// ws layout (bytes)
#define PARTIAL_OFF  0                          // 8*2*21*9216 fp32  = 12386304
#define XP_OFF       13934592                   // 2*98*98*256 fp32  = 19668992
#define AHI_OFF      33603584                   // 256*2304 f16      = 1179648
#define ALO_OFF      34783232                   // 256*2304 f16      = 1179648
#define IDX_OFF      35962880                   // 9*18432*4 int     = 2654208
#define G_OFF        38617088                   // 9*18432*4 fp32    = 2654208

__device__ __forceinline__ u16 h2u(_Float16 h) {
  return __builtin_bit_cast(unsigned short, h);
}
__device__ __forceinline__ void split16(float v, u16& hi, u16& lo) {
  _Float16 h = (_Float16)v;        // v_cvt_f16_f32, RNE
  float r = v - (float)h;          // exact residual
  _Float16 l = (_Float16)r;
  hi = h2u(h); lo = h2u(l);
}
// LDS-only barrier: waits lgkmcnt(0) but does NOT drain vmcnt — global
// prefetches stay in flight across the barrier (CK block_sync_lds pattern).
__device__ __forceinline__ void sync_lds() {
  asm volatile("s_waitcnt lgkmcnt(0)\n\ts_barrier" ::: "memory");
}

// ================= fused prep: conv(0..1151) | pad_pack(1152..2303) | pack_A(2304..2591) =================
__global__ __launch_bounds__(256) void prep1(
    const float* __restrict__ x, const float* __restrict__ w_p,
    const float* __restrict__ w_ad, const float* __restrict__ w_conv,
    float* __restrict__ partial, float* __restrict__ xp,
    u16* __restrict__ A_hi, u16* __restrict__ A_lo) {
  __shared__ float smem[4224];     // conv: 32cc x 11ch x 12 = 16896B; pad: 64x65 = 16640B
  int bx = blockIdx.x;
  int tid = threadIdx.x;

  if (bx < 1152) {
    // ---- stage-A conv: 21ch 3x3 over 256c, fp32; weights preloaded to LDS ----
    // Accumulation order (cc asc, taps 0..8 fmaf chain) BIT-IDENTICAL to r3-r7.
    int cg = bx & 1; int chunk = (bx >> 1) & 7; int r = bx >> 4;
    int tile = r % 36; int n = r / 36;
    int h0 = (tile / 6) * 16, w0 = (tile % 6) * 16;
    int chB = cg * 11; int chN = cg ? 10 : 11;

    for (int idx = tid; idx < 3168; idx += 256) {     // 32*11*9
      int tap = idx % 9; int r2 = idx / 9; int chl = r2 % 11; int cc = r2 / 11;
      int ch = chB + chl; int gc = chunk*32 + cc;
      if (ch < 21) {
        float v = (ch < 18) ? w_p[((size_t)ch*C + gc)*9 + tap]
                            : w_ad[((size_t)(ch-18)*C + gc)*9 + tap];
        smem[(cc*11 + chl)*12 + tap] = v;
      }
    }
    __syncthreads();

    int row = tid >> 4, col = tid & 15;
    int h = h0 + row, w = w0 + col;
    float acc[11];
    #pragma unroll
    for (int i = 0; i < 11; i++) acc[i] = 0.f;

    const float* xn = x + (size_t)(n*C + chunk*32) * HW;
    for (int cc = 0; cc < 32; cc++) {
      const float* xc = xn + cc * HW;
      float xr[9];
      #pragma unroll
      for (int di = 0; di < 3; di++) {
        int hg = h + di - 1;
        bool hok = ((unsigned)hg < 96u);
        #pragma unroll
        for (int dj = 0; dj < 3; dj++) {
          int wg = w + dj - 1;
          bool ok = hok && ((unsigned)wg < 96u);
          xr[di*3+dj] = ok ? xc[hg*W + wg] : 0.f;
        }
      }
      #pragma unroll
      for (int chl = 0; chl < 11; chl++) {
        if (chl < chN) {
          const float* wv = &smem[(cc*11 + chl)*12];
          float4 wa = *(const float4*)(wv);
          float4 wb = *(const float4*)(wv + 4);
          float  w8 = wv[8];
          acc[chl] = fmaf(xr[0], wa.x, acc[chl]);
          acc[chl] = fmaf(xr[1], wa.y, acc[chl]);
          acc[chl] = fmaf(xr[2], wa.z, acc[chl]);
          acc[chl] = fmaf(xr[3], wa.w, acc[chl]);
          acc[chl] = fmaf(xr[4], wb.x, acc[chl]);
          acc[chl] = fmaf(xr[5], wb.y, acc[chl]);
          acc[chl] = fmaf(xr[6], wb.z, acc[chl]);
          acc[chl] = fmaf(xr[7], wb.w, acc[chl]);
          acc[chl] = fmaf(xr[8], w8,   acc[chl]);
        }
      }
    }
    #pragma unroll
    for (int chl = 0; chl < 11; chl++) {
      if (chl < chN)
        partial[((chunk*2 + n)*21 + chB + chl)*HW + h*W + w] = acc[chl];
    }

  } else if (bx < 2304) {
    // ---- NCHW fp32 -> padded NHWC fp32 (borders pre-zeroed by memset) ----
    int pb = bx - 1152;
    int n = pb / 576; int r = pb % 576;
    int cb = r / 144; int hwb = r % 144;
    int c0 = cb * 64, hw0 = hwb * 64;
    int ii = tid & 63; int cl4 = tid >> 6;
    #pragma unroll
    for (int r2 = 0; r2 < 16; r2++) {
      int c_l = cl4*16 + r2;
      smem[c_l*65 + ii] = x[(size_t)(n*C + c0 + c_l)*HW + hw0 + ii];
    }
    __syncthreads();
    int hw = hw0 + ii;
    int h = hw / W, w = hw % W;
    float* dst = xp + ((size_t)(n*HP + h + 1)*HP + (w + 1))*C + c0 + cl4*16;
    #pragma unroll
    for (int q = 0; q < 4; q++) {
      *(float4*)(dst + q*4) = make_float4(smem[(cl4*16 + q*4 + 0)*65 + ii],
                                          smem[(cl4*16 + q*4 + 1)*65 + ii],
                                          smem[(cl4*16 + q*4 + 2)*65 + ii],
                                          smem[(cl4*16 + q*4 + 3)*65 + ii]);
    }

  } else {
    // ---- pack+split w_conv into MFMA-fragment-tiled A_hi/A_lo ----
    // e = ((((mo*72+itg)*2+mw)*4+mi)*64+lane)*8 + j holds
    //   A[o = mo*128+mw*64+mi*16+(lane&15)][kc = itg*32+(lane>>4)*8+j]
    int pb = bx - 2304;                 // 0..287
    int t = pb*256 + tid;               // 0..73727
    int e0 = t*8;
    int lane = (e0 >> 3) & 63;
    int mi   = (e0 >> 9) & 3;
    int mw   = (e0 >> 11) & 1;
    int rr   = e0 >> 12; int itg = rr % 72; int mo = rr / 72;
    int o = mo*128 + mw*64 + mi*16 + (lane & 15);
    int kcb = itg*32 + (lane >> 4)*8;
    #pragma unroll
    for (int j2 = 0; j2 < 8; j2++) {
      int kc = kcb + j2; int k = kc >> 8; int c = kc & 255;
      float a = w_conv[((size_t)o*C + c)*9 + k];
      u16 hi, lo; split16(a, hi, lo);
      A_hi[e0 + j2] = hi; A_lo[e0 + j2] = lo;
    }
  }
}

// ================= fused reduce + bilinear taps =================
// Chunk-ascending sums then +bias — bit-identical to r7's reduce_small+make_taps.
__global__ __launch_bounds__(256) void taps2(
    const float* __restrict__ partial, const float* __restrict__ b_p,
    const float* __restrict__ b_ad,
    int* __restrict__ idx_arr, float* __restrict__ g_arr) {
  int e = blockIdx.x * 256 + threadIdx.x;      // < 9*18432 = 165888
  int k = e / NS; int s = e % NS;
  int n = s / HW; int hw = s % HW;
  int h = hw / W, w = hw % W;
  int ka = 18 + (k % 3);
  float offx = 0.f, offy = 0.f, za = 0.f;
  #pragma unroll
  for (int chunk = 0; chunk < 8; chunk++) {
    const float* pb2 = partial + (size_t)((chunk*2 + n)*21)*HW + hw;
    offx += pb2[(size_t)k*HW];
    offy += pb2[(size_t)(k+9)*HW];
    za   += pb2[(size_t)ka*HW];
  }
  offx += b_p[k]; offy += b_p[k+9];
  za   += b_ad[k % 3];
  float a2 = 2.0f / (1.0f + expf(za));         // (1-sigmoid)*DIL

  float ri = (float)(k / 3) - 1.0f, rj = (float)(k % 3) - 1.0f;
  float px = (float)(h + 1) + ri + offx + a2 * ri;
  float py = (float)(w + 1) + rj + offy + a2 * rj;
  float fx = floorf(px), fy = floorf(py);
  int qltx = min(max((int)fx, 0), 97);
  int qlty = min(max((int)fy, 0), 97);
  int qrbx = min(max((int)fx + 1, 0), 97);
  int qrby = min(max((int)fy + 1, 0), 97);
  bool mx = (px < 1.0f) || (px > 96.0f);
  bool my = (py < 1.0f) || (py > 96.0f);
  float pxm = mx ? fx : px;
  float pym = my ? fy : py;
  pxm = fminf(fmaxf(pxm, 0.f), 97.f);
  pym = fminf(fmaxf(pym, 0.f), 97.f);
  float glx = 1.0f + ((float)qltx - pxm);
  float grx = 1.0f - ((float)qrbx - pxm);
  float gly = 1.0f + ((float)qlty - pym);
  float gry = 1.0f - ((float)qrby - pym);
  int base = n * HP * HP * C;
  int4 qi;
  qi.x = base + (qltx*HP + qlty)*C;   // lt
  qi.y = base + (qrbx*HP + qrby)*C;   // rb
  qi.z = base + (qltx*HP + qrby)*C;   // lb
  qi.w = base + (qrbx*HP + qlty)*C;   // rt
  float4 gg = make_float4(glx*gly, grx*gry, glx*gry, grx*gly);
  *(int4*)(idx_arr + (size_t)e*4) = qi;
  *(float4*)(g_arr  + (size_t)e*4) = gg;
}

// ================= fused gather + split-f16 MFMA GEMM =================
// XCD-swizzled; A direct-from-global (fragment-tiled); B double-buffered LDS
// with ONE lgkm-only barrier per iter. 3-term split-f16 (r7-proven math).
// grid 1152: xcd = bx&7 -> 36 contiguous sb per XCD (xp slice ~2.6MB fits L2).
__global__ __launch_bounds__(256) void gemm_def(
    const u16* __restrict__ A_hi, const u16* __restrict__ A_lo,
    const float* __restrict__ xp,
    const int* __restrict__ idx_arr, const float* __restrict__ g_arr,
    float* __restrict__ out) {
  __shared__ u16 Bh[2][64*40];
  __shared__ u16 Bl[2][64*40];
  int bx = blockIdx.x;
  int xcd = bx & 7; int jj = bx >> 3;          // jj 0..143
  int sub = jj & 3; int mo = sub & 1; int kh = sub >> 1;
  int sb = xcd*36 + (jj >> 2);                 // 0..287
  int o0 = mo * 128; int s0 = sb * 64;
  int n = s0 / HW; int hw0 = s0 % HW;
  int tid = threadIdx.x;
  int wave = tid >> 6, lane = tid & 63;
  int l16 = lane & 15, quad = lane >> 4;
  int mw = wave >> 1, nw = wave & 1;

  f32x4 acc[4][2];
  f32x4 z4 = {0.f, 0.f, 0.f, 0.f};
  #pragma unroll
  for (int i = 0; i < 4; i++) { acc[i][0] = z4; acc[i][1] = z4; }

  int s_l = tid >> 2; int cs = (tid & 3) * 8;  // B-build mapping (r7-proven)
  int sg = s0 + s_l;

  int4 qi; float4 gg;
  for (int it = 0; it < 36; it++) {
    int itg = kh*36 + it;
    int c0k = (itg & 7) * 32;
    if (it == 0 || (itg & 7) == 0) {           // qi/g hoisted per k-window
      int k = itg >> 3;
      qi = *(const int4*)(idx_arr + ((size_t)k*NS + sg)*4);
      gg = *(const float4*)(g_arr  + ((size_t)k*NS + sg)*4);
    }
    // ---- A fragments direct from global (coalesced 16B/lane, L2-hot) ----
    uint4 aH[4], aL[4];
    int abase = ((mo*72 + itg)*2 + mw)*4;
    #pragma unroll
    for (int mi = 0; mi < 4; mi++) {
      size_t off = ((size_t)(abase + mi) << 9) + lane*8;
      aH[mi] = *(const uint4*)(A_hi + off);
      aL[mi] = *(const uint4*)(A_lo + off);
    }
    // ---- taps ----
    const float* p0 = xp + qi.x + c0k + cs;
    const float* p1 = xp + qi.y + c0k + cs;
    const float* p2 = xp + qi.z + c0k + cs;
    const float* p3 = xp + qi.w + c0k + cs;
    float4 t0a = *(const float4*)(p0), t0b = *(const float4*)(p0 + 4);
    float4 t1a = *(const float4*)(p1), t1b = *(const float4*)(p1 + 4);
    float4 t2a = *(const float4*)(p2), t2b = *(const float4*)(p2 + 4);
    float4 t3a = *(const float4*)(p3), t3b = *(const float4*)(p3 + 4);
    float v[8];
    v[0] = gg.x*t0a.x + gg.y*t1a.x + gg.z*t2a.x + gg.w*t3a.x;
    v[1] = gg.x*t0a.y + gg.y*t1a.y + gg.z*t2a.y + gg.w*t3a.y;
    v[2] = gg.x*t0a.z + gg.y*t1a.z + gg.z*t2a.z + gg.w*t3a.z;
    v[3] = gg.x*t0a.w + gg.y*t1a.w + gg.z*t2a.w + gg.w*t3a.w;
    v[4] = gg.x*t0b.x + gg.y*t1b.x + gg.z*t2b.x + gg.w*t3b.x;
    v[5] = gg.x*t0b.y + gg.y*t1b.y + gg.z*t2b.y + gg.w*t3b.y;
    v[6] = gg.x*t0b.z + gg.y*t1b.z + gg.z*t2b.z + gg.w*t3b.z;
    v[7] = gg.x*t0b.w + gg.y*t1b.w + gg.z*t2b.w + gg.w*t3b.w;
    u16 hb[8], lb[8];
    #pragma unroll
    for (int j = 0; j < 8; j++) split16(v[j], hb[j], lb[j]);
    uint4 bph, bpl;
    bph.x = (u32)hb[0] | ((u32)hb[1] << 16); bph.y = (u32)hb[2] | ((u32)hb[3] << 16);
    bph.z = (u32)hb[4] | ((u32)hb[5] << 16); bph.w = (u32)hb[6] | ((u32)hb[7] << 16);
    bpl.x = (u32)lb[0] | ((u32)lb[1] << 16); bpl.y = (u32)lb[2] | ((u32)lb[3] << 16);
    bpl.z = (u32)lb[4] | ((u32)lb[5] << 16); bpl.w = (u32)lb[6] | ((u32)lb[7] << 16);
    int buf = it & 1;
    *(uint4*)(&Bh[buf][s_l*40 + cs]) = bph;
    *(uint4*)(&Bl[buf][s_l*40 + cs]) = bpl;
    sync_lds();   // single barrier/iter: visibility now, WAR via next iter's barrier
    f16x8 bfh[2], bfl[2];
    #pragma unroll
    for (int ni = 0; ni < 2; ni++) {
      int rr = (nw*32 + ni*16 + l16)*40 + quad*8;
      bfh[ni] = *(const f16x8*)(&Bh[buf][rr]);
      bfl[ni] = *(const f16x8*)(&Bl[buf][rr]);
    }
    #pragma unroll
    for (int mi = 0; mi < 4; mi++) {
      f16x8 fh = __builtin_bit_cast(f16x8, aH[mi]);
      f16x8 fl = __builtin_bit_cast(f16x8, aL[mi]);
      #pragma unroll
      for (int ni = 0; ni < 2; ni++) {
        acc[mi][ni] = __builtin_amdgcn_mfma_f32_16x16x32_f16(fh, bfh[ni], acc[mi][ni], 0, 0, 0);
        acc[mi][ni] = __builtin_amdgcn_mfma_f32_16x16x32_f16(fh, bfl[ni], acc[mi][ni], 0, 0, 0);
        acc[mi][ni] = __builtin_amdgcn_mfma_f32_16x16x32_f16(fl, bfh[ni], acc[mi][ni], 0, 0, 0);
      }
    }
  }
  // ---- epilogue: split-K accumulate ----
  #pragma unroll
  for (int mi = 0; mi < 4; mi++)
    #pragma unroll
    for (int ni = 0; ni < 2; ni++) {
      int hw = hw0 + nw*32 + ni*16 + l16;
      #pragma unroll
      for (int rr = 0; rr < 4; rr++) {
        int o = o0 + mw*64 + mi*16 + quad*4 + rr;
        atomicAdd(&out[(size_t)(n*OC + o)*HW + hw], acc[mi][ni][rr]);
      }
    }
}

extern "C" void kernel_launch(void* const* d_in, const int* in_sizes, int n_in,
                              void* d_out, int out_size, void* d_ws, size_t ws_size,
                              hipStream_t stream) {
  const float* x      = (const float*)d_in[0];
  const float* w_p    = (const float*)d_in[1];
  const float* b_p    = (const float*)d_in[2];
  const float* w_ad   = (const float*)d_in[3];
  const float* b_ad   = (const float*)d_in[4];
  const float* w_conv = (const float*)d_in[5];
  float* out = (float*)d_out;

  char* ws = (char*)d_ws;
  float* partial = (float*)(ws + PARTIAL_OFF);
  float* xp      = (float*)(ws + XP_OFF);
  u16*   A_hi    = (u16*)  (ws + AHI_OFF);
  u16*   A_lo    = (u16*)  (ws + ALO_OFF);
  int*   idx_arr = (int*)  (ws + IDX_OFF);
  float* g_arr   = (float*)(ws + G_OFF);

  hipMemsetAsync(xp, 0, (size_t)NB*HP*HP*C*sizeof(float), stream);
  hipMemsetAsync(out, 0, (size_t)out_size*sizeof(float), stream);

  prep1   <<<2592, 256, 0, stream>>>(x, w_p, w_ad, w_conv, partial, xp, A_hi, A_lo);
  taps2   <<<648,  256, 0, stream>>>(partial, b_p, b_ad, idx_arr, g_arr);
  gemm_def<<<1152, 256, 0, stream>>>(A_hi, A_lo, xp, idx_arr, g_arr, out);
}

// Round 9
// 248.521 us; speedup vs baseline: 2.1812x; 1.0221x over previous
//
#include <hip/hip_runtime.h>
#include <math.h>

typedef unsigned short u16;
typedef unsigned int   u32;

typedef __attribute__((ext_vector_type(8))) _Float16 f16x8;
typedef __attribute__((ext_vector_type(4))) float    f32x4;

// ---------- constants ----------
#define NB   2
#define C    256
#define H    96
#define W    96
#define HW   (H*W)          // 9216
#define HP   98
#define OC   256
#define KDIM (9*C)          // 2304
#define NS   (NB*HW)        // 18432 spatial columns

// ws layout (bytes)
#define PARTIAL_OFF  0                          // 8*2*21*9216 fp32  = 12386304
#define XP_OFF       13934592                   // 2*98*98*256 fp32  = 19668992
#define AHI_OFF      33603584                   // 256*2304 f16      = 1179648
#define ALO_OFF      34783232                   // 256*2304 f16      = 1179648
#define IDX_OFF      35962880                   // 9*18432*4 int     = 2654208
#define G_OFF        38617088                   // 9*18432*4 fp32    = 2654208

__device__ __forceinline__ u16 h2u(_Float16 h) {
  return __builtin_bit_cast(unsigned short, h);
}
__device__ __forceinline__ void split16(float v, u16& hi, u16& lo) {
  _Float16 h = (_Float16)v;        // v_cvt_f16_f32, RNE
  float r = v - (float)h;          // exact residual
  _Float16 l = (_Float16)r;
  hi = h2u(h); lo = h2u(l);
}
// LDS-only barrier: waits lgkmcnt(0) but does NOT drain vmcnt — global
// prefetches stay in flight across the barrier (CK block_sync_lds pattern).
__device__ __forceinline__ void sync_lds() {
  asm volatile("s_waitcnt lgkmcnt(0)\n\ts_barrier" ::: "memory");
}

// ================= fused prep: conv(0..287) | pad_pack(288..1439) | pack_A(1440..1727) =================
__global__ __launch_bounds__(256) void prep1(
    const float* __restrict__ x, const float* __restrict__ w_p,
    const float* __restrict__ w_ad, const float* __restrict__ w_conv,
    float* __restrict__ partial, float* __restrict__ xp,
    u16* __restrict__ A_hi, u16* __restrict__ A_lo) {
  __shared__ float smem[4224];     // conv: 32cc x 11ch x 12 = 16896B; pad: 64x65 = 16640B
  int bx = blockIdx.x;
  int tid = threadIdx.x;

  if (bx < 288) {
    // ---- stage-A conv: 21ch 3x3 over 256c, fp32; 4 px/thread (32x32 tile).
    // Per-output accumulation order (cc asc, taps di,dj asc, fmaf chain) is
    // BIT-IDENTICAL to rounds 3-8 — offsets unchanged, no floor-flip risk.
    int cg = bx & 1; int chunk = (bx >> 1) & 7; int r = bx >> 4;   // r 0..17
    int tile = r % 9; int n = r / 9;
    int h0 = (tile / 3) * 32, w0 = (tile % 3) * 32;
    int chB = cg * 11; int chN = cg ? 10 : 11;

    for (int idx = tid; idx < 3168; idx += 256) {     // 32*11*9
      int tap = idx % 9; int r2 = idx / 9; int chl = r2 % 11; int cc = r2 / 11;
      int ch = chB + chl; int gc = chunk*32 + cc;
      if (ch < 21) {
        float v = (ch < 18) ? w_p[((size_t)ch*C + gc)*9 + tap]
                            : w_ad[((size_t)(ch-18)*C + gc)*9 + tap];
        smem[(cc*11 + chl)*12 + tap] = v;
      }
    }
    __syncthreads();

    int row = tid >> 3, col0 = (tid & 7) * 4;
    int h = h0 + row, w = w0 + col0;

    float acc[11][4];
    #pragma unroll
    for (int i = 0; i < 11; i++)
      { acc[i][0]=0.f; acc[i][1]=0.f; acc[i][2]=0.f; acc[i][3]=0.f; }

    const float* xn = x + (size_t)(n*C + chunk*32) * HW;
    for (int cc = 0; cc < 32; cc++) {
      const float* xc = xn + cc * HW;
      float xr[3][6];
      #pragma unroll
      for (int di = 0; di < 3; di++) {
        int hg = h + di - 1;
        bool hok = ((unsigned)hg < 96u);
        #pragma unroll
        for (int jj = 0; jj < 6; jj++) {
          int wg = w + jj - 1;
          bool ok = hok && ((unsigned)wg < 96u);
          xr[di][jj] = ok ? xc[hg*W + wg] : 0.f;
        }
      }
      #pragma unroll
      for (int chl = 0; chl < 11; chl++) {
        if (chl < chN) {                       // block-uniform bound
          const float* wv = &smem[(cc*11 + chl)*12];
          float4 wa = *(const float4*)(wv);
          float4 wb = *(const float4*)(wv + 4);
          float  w8 = wv[8];
          float wt[9] = {wa.x, wa.y, wa.z, wa.w, wb.x, wb.y, wb.z, wb.w, w8};
          #pragma unroll
          for (int di = 0; di < 3; di++)
            #pragma unroll
            for (int dj = 0; dj < 3; dj++) {
              float wgt = wt[di*3 + dj];
              #pragma unroll
              for (int j = 0; j < 4; j++)
                acc[chl][j] = fmaf(xr[di][dj + j], wgt, acc[chl][j]);
            }
        }
      }
    }
    #pragma unroll
    for (int chl = 0; chl < 11; chl++) {
      if (chl < chN) {
        int off = ((chunk*2 + n)*21 + chB + chl)*HW + h*W + w;
        *(float4*)(partial + off) = make_float4(acc[chl][0], acc[chl][1],
                                                acc[chl][2], acc[chl][3]);
      }
    }

  } else if (bx < 1440) {
    // ---- NCHW fp32 -> padded NHWC fp32 (borders pre-zeroed by memset) ----
    int pb = bx - 288;
    int n = pb / 576; int r = pb % 576;
    int cb = r / 144; int hwb = r % 144;
    int c0 = cb * 64, hw0 = hwb * 64;
    int ii = tid & 63; int cl4 = tid >> 6;
    #pragma unroll
    for (int r2 = 0; r2 < 16; r2++) {
      int c_l = cl4*16 + r2;
      smem[c_l*65 + ii] = x[(size_t)(n*C + c0 + c_l)*HW + hw0 + ii];
    }
    __syncthreads();
    int hw = hw0 + ii;
    int h = hw / W, w = hw % W;
    float* dst = xp + ((size_t)(n*HP + h + 1)*HP + (w + 1))*C + c0 + cl4*16;
    #pragma unroll
    for (int q = 0; q < 4; q++) {
      *(float4*)(dst + q*4) = make_float4(smem[(cl4*16 + q*4 + 0)*65 + ii],
                                          smem[(cl4*16 + q*4 + 1)*65 + ii],
                                          smem[(cl4*16 + q*4 + 2)*65 + ii],
                                          smem[(cl4*16 + q*4 + 3)*65 + ii]);
    }

  } else {
    // ---- pack+split w_conv into MFMA-fragment-tiled A_hi/A_lo ----
    // e = ((((mo*72+itg)*2+mw)*4+mi)*64+lane)*8 + j holds
    //   A[o = mo*128+mw*64+mi*16+(lane&15)][kc = itg*32+(lane>>4)*8+j]
    int pb = bx - 1440;                 // 0..287
    int t = pb*256 + tid;               // 0..73727
    int e0 = t*8;
    int lane = (e0 >> 3) & 63;
    int mi   = (e0 >> 9) & 3;
    int mw   = (e0 >> 11) & 1;
    int rr   = e0 >> 12; int itg = rr % 72; int mo = rr / 72;
    int o = mo*128 + mw*64 + mi*16 + (lane & 15);
    int kcb = itg*32 + (lane >> 4)*8;
    #pragma unroll
    for (int j2 = 0; j2 < 8; j2++) {
      int kc = kcb + j2; int k = kc >> 8; int c = kc & 255;
      float a = w_conv[((size_t)o*C + c)*9 + k];
      u16 hi, lo; split16(a, hi, lo);
      A_hi[e0 + j2] = hi; A_lo[e0 + j2] = lo;
    }
  }
}

// ================= fused reduce + bilinear taps =================
// Chunk-ascending sums then +bias — bit-identical to r7/r8.
__global__ __launch_bounds__(256) void taps2(
    const float* __restrict__ partial, const float* __restrict__ b_p,
    const float* __restrict__ b_ad,
    int* __restrict__ idx_arr, float* __restrict__ g_arr) {
  int e = blockIdx.x * 256 + threadIdx.x;      // < 9*18432 = 165888
  int k = e / NS; int s = e % NS;
  int n = s / HW; int hw = s % HW;
  int h = hw / W, w = hw % W;
  int ka = 18 + (k % 3);
  float offx = 0.f, offy = 0.f, za = 0.f;
  #pragma unroll
  for (int chunk = 0; chunk < 8; chunk++) {
    const float* pb2 = partial + (size_t)((chunk*2 + n)*21)*HW + hw;
    offx += pb2[(size_t)k*HW];
    offy += pb2[(size_t)(k+9)*HW];
    za   += pb2[(size_t)ka*HW];
  }
  offx += b_p[k]; offy += b_p[k+9];
  za   += b_ad[k % 3];
  float a2 = 2.0f / (1.0f + expf(za));         // (1-sigmoid)*DIL

  float ri = (float)(k / 3) - 1.0f, rj = (float)(k % 3) - 1.0f;
  float px = (float)(h + 1) + ri + offx + a2 * ri;
  float py = (float)(w + 1) + rj + offy + a2 * rj;
  float fx = floorf(px), fy = floorf(py);
  int qltx = min(max((int)fx, 0), 97);
  int qlty = min(max((int)fy, 0), 97);
  int qrbx = min(max((int)fx + 1, 0), 97);
  int qrby = min(max((int)fy + 1, 0), 97);
  bool mx = (px < 1.0f) || (px > 96.0f);
  bool my = (py < 1.0f) || (py > 96.0f);
  float pxm = mx ? fx : px;
  float pym = my ? fy : py;
  pxm = fminf(fmaxf(pxm, 0.f), 97.f);
  pym = fminf(fmaxf(pym, 0.f), 97.f);
  float glx = 1.0f + ((float)qltx - pxm);
  float grx = 1.0f - ((float)qrbx - pxm);
  float gly = 1.0f + ((float)qlty - pym);
  float gry = 1.0f - ((float)qrby - pym);
  int base = n * HP * HP * C;
  int4 qi;
  qi.x = base + (qltx*HP + qlty)*C;   // lt
  qi.y = base + (qrbx*HP + qrby)*C;   // rb
  qi.z = base + (qltx*HP + qrby)*C;   // lb
  qi.w = base + (qrbx*HP + qlty)*C;   // rt
  float4 gg = make_float4(glx*gly, grx*gry, glx*gry, grx*gly);
  *(int4*)(idx_arr + (size_t)e*4) = qi;
  *(float4*)(g_arr  + (size_t)e*4) = gg;
}

// ================= fused gather + split-f16 MFMA GEMM, M=256 tile =================
// One block computes ALL 256 o x 64 s (K-half). Each wave: 64 o (4 m-frags) x
// 64 s (4 n-frags) = 48 MFMA/iter — 2x MFMA per B-build vs r8, same VALU.
// A direct-from-global (fragment-tiled, L2-hot); B double-buffered LDS with ONE
// lgkm-only barrier/iter. XCD-swizzled: 36 contiguous sb per XCD (~2.6MB L2 slice).
// grid 576 = xcd(8) x [kh(2) x sbl(36)].
__global__ __launch_bounds__(256) void gemm_def(
    const u16* __restrict__ A_hi, const u16* __restrict__ A_lo,
    const float* __restrict__ xp,
    const int* __restrict__ idx_arr, const float* __restrict__ g_arr,
    float* __restrict__ out) {
  __shared__ u16 Bh[2][64*40];
  __shared__ u16 Bl[2][64*40];
  int bx = blockIdx.x;
  int xcd = bx & 7; int jj = bx >> 3;          // jj 0..71
  int kh = jj & 1; int sbl = jj >> 1;          // sbl 0..35
  int sb = xcd*36 + sbl;                       // 0..287
  int s0 = sb * 64;
  int n = s0 / HW; int hw0 = s0 % HW;
  int tid = threadIdx.x;
  int wave = tid >> 6, lane = tid & 63;
  int l16 = lane & 15, quad = lane >> 4;
  int mo = wave >> 1, mw = wave & 1;           // A-layout frag coords (o = wave*64 + ...)

  f32x4 acc[4][4];
  f32x4 z4 = {0.f, 0.f, 0.f, 0.f};
  #pragma unroll
  for (int i = 0; i < 4; i++)
    { acc[i][0] = z4; acc[i][1] = z4; acc[i][2] = z4; acc[i][3] = z4; }

  int s_l = tid >> 2; int cs = (tid & 3) * 8;  // B-build mapping (r7/r8-proven)
  int sg = s0 + s_l;

  int4 qi; float4 gg;
  for (int it = 0; it < 36; it++) {
    int itg = kh*36 + it;
    int c0k = (itg & 7) * 32;
    if (it == 0 || (itg & 7) == 0) {           // qi/g hoisted per k-window
      int k = itg >> 3;
      qi = *(const int4*)(idx_arr + ((size_t)k*NS + sg)*4);
      gg = *(const float4*)(g_arr  + ((size_t)k*NS + sg)*4);
    }
    // ---- A fragments direct from global (coalesced 16B/lane, L2-hot) ----
    uint4 aH[4], aL[4];
    int abase = ((mo*72 + itg)*2 + mw)*4;
    #pragma unroll
    for (int mi = 0; mi < 4; mi++) {
      size_t off = ((size_t)(abase + mi) << 9) + lane*8;
      aH[mi] = *(const uint4*)(A_hi + off);
      aL[mi] = *(const uint4*)(A_lo + off);
    }
    // ---- taps ----
    const float* p0 = xp + qi.x + c0k + cs;
    const float* p1 = xp + qi.y + c0k + cs;
    const float* p2 = xp + qi.z + c0k + cs;
    const float* p3 = xp + qi.w + c0k + cs;
    float4 t0a = *(const float4*)(p0), t0b = *(const float4*)(p0 + 4);
    float4 t1a = *(const float4*)(p1), t1b = *(const float4*)(p1 + 4);
    float4 t2a = *(const float4*)(p2), t2b = *(const float4*)(p2 + 4);
    float4 t3a = *(const float4*)(p3), t3b = *(const float4*)(p3 + 4);
    float v[8];
    v[0] = gg.x*t0a.x + gg.y*t1a.x + gg.z*t2a.x + gg.w*t3a.x;
    v[1] = gg.x*t0a.y + gg.y*t1a.y + gg.z*t2a.y + gg.w*t3a.y;
    v[2] = gg.x*t0a.z + gg.y*t1a.z + gg.z*t2a.z + gg.w*t3a.z;
    v[3] = gg.x*t0a.w + gg.y*t1a.w + gg.z*t2a.w + gg.w*t3a.w;
    v[4] = gg.x*t0b.x + gg.y*t1b.x + gg.z*t2b.x + gg.w*t3b.x;
    v[5] = gg.x*t0b.y + gg.y*t1b.y + gg.z*t2b.y + gg.w*t3b.y;
    v[6] = gg.x*t0b.z + gg.y*t1b.z + gg.z*t2b.z + gg.w*t3b.z;
    v[7] = gg.x*t0b.w + gg.y*t1b.w + gg.z*t2b.w + gg.w*t3b.w;
    u16 hb[8], lb[8];
    #pragma unroll
    for (int j = 0; j < 8; j++) split16(v[j], hb[j], lb[j]);
    uint4 bph, bpl;
    bph.x = (u32)hb[0] | ((u32)hb[1] << 16); bph.y = (u32)hb[2] | ((u32)hb[3] << 16);
    bph.z = (u32)hb[4] | ((u32)hb[5] << 16); bph.w = (u32)hb[6] | ((u32)hb[7] << 16);
    bpl.x = (u32)lb[0] | ((u32)lb[1] << 16); bpl.y = (u32)lb[2] | ((u32)lb[3] << 16);
    bpl.z = (u32)lb[4] | ((u32)lb[5] << 16); bpl.w = (u32)lb[6] | ((u32)lb[7] << 16);
    int buf = it & 1;
    *(uint4*)(&Bh[buf][s_l*40 + cs]) = bph;
    *(uint4*)(&Bl[buf][s_l*40 + cs]) = bpl;
    sync_lds();   // single barrier/iter: visibility now, WAR via next iter's barrier
    f16x8 bfh[4], bfl[4];
    #pragma unroll
    for (int ni = 0; ni < 4; ni++) {
      int rr = (ni*16 + l16)*40 + quad*8;
      bfh[ni] = *(const f16x8*)(&Bh[buf][rr]);
      bfl[ni] = *(const f16x8*)(&Bl[buf][rr]);
    }
    #pragma unroll
    for (int mi = 0; mi < 4; mi++) {
      f16x8 fh = __builtin_bit_cast(f16x8, aH[mi]);
      f16x8 fl = __builtin_bit_cast(f16x8, aL[mi]);
      #pragma unroll
      for (int ni = 0; ni < 4; ni++) {
        acc[mi][ni] = __builtin_amdgcn_mfma_f32_16x16x32_f16(fh, bfh[ni], acc[mi][ni], 0, 0, 0);
        acc[mi][ni] = __builtin_amdgcn_mfma_f32_16x16x32_f16(fh, bfl[ni], acc[mi][ni], 0, 0, 0);
        acc[mi][ni] = __builtin_amdgcn_mfma_f32_16x16x32_f16(fl, bfh[ni], acc[mi][ni], 0, 0, 0);
      }
    }
  }
  // ---- epilogue: split-K accumulate ----
  #pragma unroll
  for (int mi = 0; mi < 4; mi++)
    #pragma unroll
    for (int ni = 0; ni < 4; ni++) {
      int hw = hw0 + ni*16 + l16;
      #pragma unroll
      for (int rr = 0; rr < 4; rr++) {
        int o = wave*64 + mi*16 + quad*4 + rr;
        atomicAdd(&out[(size_t)(n*OC + o)*HW + hw], acc[mi][ni][rr]);
      }
    }
}

extern "C" void kernel_launch(void* const* d_in, const int* in_sizes, int n_in,
                              void* d_out, int out_size, void* d_ws, size_t ws_size,
                              hipStream_t stream) {
  const float* x      = (const float*)d_in[0];
  const float* w_p    = (const float*)d_in[1];
  const float* b_p    = (const float*)d_in[2];
  const float* w_ad   = (const float*)d_in[3];
  const float* b_ad   = (const float*)d_in[4];
  const float* w_conv = (const float*)d_in[5];
  float* out = (float*)d_out;

  char* ws = (char*)d_ws;
  float* partial = (float*)(ws + PARTIAL_OFF);
  float* xp      = (float*)(ws + XP_OFF);
  u16*   A_hi    = (u16*)  (ws + AHI_OFF);
  u16*   A_lo    = (u16*)  (ws + ALO_OFF);
  int*   idx_arr = (int*)  (ws + IDX_OFF);
  float* g_arr   = (float*)(ws + G_OFF);

  hipMemsetAsync(xp, 0, (size_t)NB*HP*HP*C*sizeof(float), stream);
  hipMemsetAsync(out, 0, (size_t)out_size*sizeof(float), stream);

  prep1   <<<1728, 256, 0, stream>>>(x, w_p, w_ad, w_conv, partial, xp, A_hi, A_lo);
  taps2   <<<648,  256, 0, stream>>>(partial, b_p, b_ad, idx_arr, g_arr);
  gemm_def<<<576,  256, 0, stream>>>(A_hi, A_lo, xp, idx_arr, g_arr, out);
}

// Round 11
// 219.269 us; speedup vs baseline: 2.4722x; 1.1334x over previous
//
#include <hip/hip_runtime.h>
#include <math.h>

typedef unsigned short u16;
typedef unsigned int   u32;

typedef __attribute__((ext_vector_type(8))) _Float16 f16x8;
typedef __attribute__((ext_vector_type(4))) float    f32x4;

// ---------- constants ----------
#define NB   2
#define C    256
#define H    96
#define W    96
#define HW   (H*W)          // 9216
#define HP   98
#define OC   256
#define KDIM (9*C)          // 2304
#define NS   (NB*HW)        // 18432 spatial columns

// ws layout (bytes)
#define XP_OFF    0                      // 2*98*98*256 fp32 = 19668992
#define AHI_OFF   19668992               // 256*2304 f16     = 1179648
#define ALO_OFF   20848640               // 256*2304 f16     = 1179648
#define A2HI_OFF  22028288               // 32*2304 f16      = 147456
#define A2LO_OFF  22175744               // 32*2304 f16      = 147456
#define OFF2_OFF  22323200               // 21*18432 fp32    = 1548288
#define IDX_OFF   23871488               // 9*18432*4 int    = 2654208
#define G_OFF     26525696               // 9*18432*4 fp32   = 2654208
// end 29179904

__device__ __forceinline__ u16 h2u(_Float16 h) {
  return __builtin_bit_cast(unsigned short, h);
}
__device__ __forceinline__ void split16(float v, u16& hi, u16& lo) {
  _Float16 h = (_Float16)v;        // v_cvt_f16_f32, RNE
  float r = v - (float)h;          // exact residual
  _Float16 l = (_Float16)r;
  hi = h2u(h); lo = h2u(l);
}
// LDS-only barrier: waits lgkmcnt(0) but does NOT drain vmcnt.
__device__ __forceinline__ void sync_lds() {
  asm volatile("s_waitcnt lgkmcnt(0)\n\ts_barrier" ::: "memory");
}

// ================= prep: pad_pack(0..1151) | pack_A(1152..1439) | pack_A2(1440..1475) =================
__global__ __launch_bounds__(256) void prep1(
    const float* __restrict__ x, const float* __restrict__ w_p,
    const float* __restrict__ w_ad, const float* __restrict__ w_conv,
    float* __restrict__ xp,
    u16* __restrict__ A_hi, u16* __restrict__ A_lo,
    u16* __restrict__ A2_hi, u16* __restrict__ A2_lo) {
  __shared__ float smem[64*65];
  int bx = blockIdx.x;
  int tid = threadIdx.x;

  if (bx < 1152) {
    // ---- NCHW fp32 -> padded NHWC fp32 (borders pre-zeroed by memset) ----
    int pb = bx;
    int n = pb / 576; int r = pb % 576;
    int cb = r / 144; int hwb = r % 144;
    int c0 = cb * 64, hw0 = hwb * 64;
    int ii = tid & 63; int cl4 = tid >> 6;
    #pragma unroll
    for (int r2 = 0; r2 < 16; r2++) {
      int c_l = cl4*16 + r2;
      smem[c_l*65 + ii] = x[(size_t)(n*C + c0 + c_l)*HW + hw0 + ii];
    }
    __syncthreads();
    int hw = hw0 + ii;
    int h = hw / W, w = hw % W;
    float* dst = xp + ((size_t)(n*HP + h + 1)*HP + (w + 1))*C + c0 + cl4*16;
    #pragma unroll
    for (int q = 0; q < 4; q++) {
      *(float4*)(dst + q*4) = make_float4(smem[(cl4*16 + q*4 + 0)*65 + ii],
                                          smem[(cl4*16 + q*4 + 1)*65 + ii],
                                          smem[(cl4*16 + q*4 + 2)*65 + ii],
                                          smem[(cl4*16 + q*4 + 3)*65 + ii]);
    }

  } else if (bx < 1440) {
    // ---- pack+split w_conv into MFMA-fragment-tiled A_hi/A_lo (r8/r9-proven) ----
    // e = ((((mo*72+itg)*2+mw)*4+mi)*64+lane)*8 + j holds
    //   A[o = mo*128+mw*64+mi*16+(lane&15)][kc = itg*32+(lane>>4)*8+j]
    int pb = bx - 1152;                 // 0..287
    int t = pb*256 + tid;               // 0..73727
    int e0 = t*8;
    int lane = (e0 >> 3) & 63;
    int mi   = (e0 >> 9) & 3;
    int mw   = (e0 >> 11) & 1;
    int rr   = e0 >> 12; int itg = rr % 72; int mo = rr / 72;
    int o = mo*128 + mw*64 + mi*16 + (lane & 15);
    int kcb = itg*32 + (lane >> 4)*8;
    #pragma unroll
    for (int j2 = 0; j2 < 8; j2++) {
      int kc = kcb + j2; int k = kc >> 8; int c = kc & 255;
      float a = w_conv[((size_t)o*C + c)*9 + k];
      u16 hi, lo; split16(a, hi, lo);
      A_hi[e0 + j2] = hi; A_lo[e0 + j2] = lo;
    }

  } else {
    // ---- pack+split stage-A weights into frag-tiled A2 (M=32: 0..17 w_p, 18..20 w_ad, pad 0) ----
    // e = ((itg*2+mi)*64+lane)*8 + j holds A2[o = mi*16+(lane&15)][kc = itg*32+(lane>>4)*8+j]
    int pb = bx - 1440;                 // 0..35
    int t = pb*256 + tid;               // 0..9215
    int e0 = t*8;
    int lane = (e0 >> 3) & 63;
    int mi   = (e0 >> 9) & 1;
    int itg  = e0 >> 10;                // 0..71
    int o = mi*16 + (lane & 15);
    int kcb = itg*32 + (lane >> 4)*8;
    #pragma unroll
    for (int j2 = 0; j2 < 8; j2++) {
      int kc = kcb + j2; int tap = kc >> 8; int c = kc & 255;
      float a = 0.f;
      if (o < 18)       a = w_p [((size_t)o*C + c)*9 + tap];
      else if (o < 21)  a = w_ad[((size_t)(o-18)*C + c)*9 + tap];
      u16 hi, lo; split16(a, hi, lo);
      A2_hi[e0 + j2] = hi; A2_lo[e0 + j2] = lo;
    }
  }
}

// ================= stage-A conv as split-f16 MFMA: C2[21][NS] = W2 * im2col(xp) =================
// Same skeleton as gemm_def (B double-buffer, one sync_lds/iter, 3-term split),
// M=32 (2 frags shared by all waves), each wave owns 16 s-columns.
// B2[(tap*256+c)][s=(n,h,w)] = xp[n][h+tap/3][w+tap%3][c]  (static 1-pointer gather).
// grid 576 = xcd(8) x [kh(2) x sbl(36)]; split-K via atomicAdd into off2 (pre-zeroed).
__global__ __launch_bounds__(256) void conv_mfma(
    const u16* __restrict__ A2_hi, const u16* __restrict__ A2_lo,
    const float* __restrict__ xp, float* __restrict__ off2) {
  __shared__ u16 Bh[2][64*40];
  __shared__ u16 Bl[2][64*40];
  int bx = blockIdx.x;
  int xcd = bx & 7; int jj = bx >> 3;          // jj 0..71
  int kh = jj & 1; int sbl = jj >> 1;          // sbl 0..35
  int sb = xcd*36 + sbl;                       // 0..287
  int s0 = sb * 64;
  int tid = threadIdx.x;
  int wave = tid >> 6, lane = tid & 63;
  int l16 = lane & 15, quad = lane >> 4;

  f32x4 acc[2];
  f32x4 z4 = {0.f, 0.f, 0.f, 0.f};
  acc[0] = z4; acc[1] = z4;

  int s_l = tid >> 2; int cs = (tid & 3) * 8;  // B-build map (r7-r9 proven)
  int sg = s0 + s_l;
  int n = sg / HW; int hw = sg % HW;
  int h = hw / W, w = hw % W;
  const float* sbase = xp + ((size_t)(n*HP + h)*HP + w)*C;   // padded top-left

  for (int it = 0; it < 36; it++) {
    int itg = kh*36 + it;
    int tap = itg >> 3;
    int di = tap / 3, dj = tap % 3;
    int c0k = (itg & 7) * 32;
    // ---- A2 fragments (tiny, L2-hot; identical across waves) ----
    uint4 aH[2], aL[2];
    #pragma unroll
    for (int mi = 0; mi < 2; mi++) {
      size_t off = ((size_t)(itg*2 + mi) << 9) + lane*8;
      aH[mi] = *(const uint4*)(A2_hi + off);
      aL[mi] = *(const uint4*)(A2_lo + off);
    }
    // ---- B2 taps: one contiguous 32B read ----
    const float* p0 = sbase + (di*HP + dj)*C + c0k + cs;
    float4 ta = *(const float4*)(p0), tb = *(const float4*)(p0 + 4);
    float v[8] = {ta.x, ta.y, ta.z, ta.w, tb.x, tb.y, tb.z, tb.w};
    u16 hb[8], lb[8];
    #pragma unroll
    for (int j = 0; j < 8; j++) split16(v[j], hb[j], lb[j]);
    uint4 bph, bpl;
    bph.x = (u32)hb[0] | ((u32)hb[1] << 16); bph.y = (u32)hb[2] | ((u32)hb[3] << 16);
    bph.z = (u32)hb[4] | ((u32)hb[5] << 16); bph.w = (u32)hb[6] | ((u32)hb[7] << 16);
    bpl.x = (u32)lb[0] | ((u32)lb[1] << 16); bpl.y = (u32)lb[2] | ((u32)lb[3] << 16);
    bpl.z = (u32)lb[4] | ((u32)lb[5] << 16); bpl.w = (u32)lb[6] | ((u32)lb[7] << 16);
    int buf = it & 1;
    *(uint4*)(&Bh[buf][s_l*40 + cs]) = bph;
    *(uint4*)(&Bl[buf][s_l*40 + cs]) = bpl;
    sync_lds();
    int rr = (wave*16 + l16)*40 + quad*8;
    f16x8 bfh = *(const f16x8*)(&Bh[buf][rr]);
    f16x8 bfl = *(const f16x8*)(&Bl[buf][rr]);
    #pragma unroll
    for (int mi = 0; mi < 2; mi++) {
      f16x8 fh = __builtin_bit_cast(f16x8, aH[mi]);
      f16x8 fl = __builtin_bit_cast(f16x8, aL[mi]);
      acc[mi] = __builtin_amdgcn_mfma_f32_16x16x32_f16(fh, bfh, acc[mi], 0, 0, 0);
      acc[mi] = __builtin_amdgcn_mfma_f32_16x16x32_f16(fh, bfl, acc[mi], 0, 0, 0);
      acc[mi] = __builtin_amdgcn_mfma_f32_16x16x32_f16(fl, bfh, acc[mi], 0, 0, 0);
    }
  }
  // ---- epilogue: rows <21 accumulate into off2 ----
  int sout = s0 + wave*16 + l16;
  #pragma unroll
  for (int mi = 0; mi < 2; mi++)
    #pragma unroll
    for (int rr2 = 0; rr2 < 4; rr2++) {
      int o = mi*16 + quad*4 + rr2;
      if (o < 21)
        atomicAdd(&off2[(size_t)o*NS + sout], acc[mi][rr2]);
    }
}

// ================= bilinear taps (reads off2 directly) =================
__global__ __launch_bounds__(256) void taps2(
    const float* __restrict__ off2, const float* __restrict__ b_p,
    const float* __restrict__ b_ad,
    int* __restrict__ idx_arr, float* __restrict__ g_arr) {
  int e = blockIdx.x * 256 + threadIdx.x;      // < 9*18432 = 165888
  int k = e / NS; int s = e % NS;
  int n = s / HW; int hw = s % HW;
  int h = hw / W, w = hw % W;
  float offx = off2[(size_t)k*NS + s]            + b_p[k];
  float offy = off2[(size_t)(k+9)*NS + s]        + b_p[k+9];
  float za   = off2[(size_t)(18 + (k%3))*NS + s] + b_ad[k % 3];
  float a2 = 2.0f / (1.0f + expf(za));         // (1-sigmoid)*DIL

  float ri = (float)(k / 3) - 1.0f, rj = (float)(k % 3) - 1.0f;
  float px = (float)(h + 1) + ri + offx + a2 * ri;
  float py = (float)(w + 1) + rj + offy + a2 * rj;
  float fx = floorf(px), fy = floorf(py);
  int qltx = min(max((int)fx, 0), 97);
  int qlty = min(max((int)fy, 0), 97);
  int qrbx = min(max((int)fx + 1, 0), 97);
  int qrby = min(max((int)fy + 1, 0), 97);
  bool mx = (px < 1.0f) || (px > 96.0f);
  bool my = (py < 1.0f) || (py > 96.0f);
  float pxm = mx ? fx : px;
  float pym = my ? fy : py;
  pxm = fminf(fmaxf(pxm, 0.f), 97.f);
  pym = fminf(fmaxf(pym, 0.f), 97.f);
  float glx = 1.0f + ((float)qltx - pxm);
  float grx = 1.0f - ((float)qrbx - pxm);
  float gly = 1.0f + ((float)qlty - pym);
  float gry = 1.0f - ((float)qrby - pym);
  int base = n * HP * HP * C;
  int4 qi;
  qi.x = base + (qltx*HP + qlty)*C;   // lt
  qi.y = base + (qrbx*HP + qrby)*C;   // rb
  qi.z = base + (qltx*HP + qrby)*C;   // lb
  qi.w = base + (qrbx*HP + qlty)*C;   // rt
  float4 gg = make_float4(glx*gly, grx*gry, glx*gry, grx*gly);
  *(int4*)(idx_arr + (size_t)e*4) = qi;
  *(float4*)(g_arr  + (size_t)e*4) = gg;
}

// ================= fused gather + split-f16 MFMA GEMM, M=256 (r9 body, PROVEN) =================
__global__ __launch_bounds__(256) void gemm_def(
    const u16* __restrict__ A_hi, const u16* __restrict__ A_lo,
    const float* __restrict__ xp,
    const int* __restrict__ idx_arr, const float* __restrict__ g_arr,
    float* __restrict__ out) {
  __shared__ u16 Bh[2][64*40];
  __shared__ u16 Bl[2][64*40];
  int bx = blockIdx.x;
  int xcd = bx & 7; int jj = bx >> 3;          // jj 0..71
  int kh = jj & 1; int sbl = jj >> 1;          // sbl 0..35
  int sb = xcd*36 + sbl;                       // 0..287
  int s0 = sb * 64;
  int n = s0 / HW; int hw0 = s0 % HW;
  int tid = threadIdx.x;
  int wave = tid >> 6, lane = tid & 63;
  int l16 = lane & 15, quad = lane >> 4;
  int mo = wave >> 1, mw = wave & 1;           // A-layout frag coords

  f32x4 acc[4][4];
  f32x4 z4 = {0.f, 0.f, 0.f, 0.f};
  #pragma unroll
  for (int i = 0; i < 4; i++)
    { acc[i][0] = z4; acc[i][1] = z4; acc[i][2] = z4; acc[i][3] = z4; }

  int s_l = tid >> 2; int cs = (tid & 3) * 8;  // B-build mapping
  int sg = s0 + s_l;

  int4 qi; float4 gg;
  for (int it = 0; it < 36; it++) {
    int itg = kh*36 + it;
    int c0k = (itg & 7) * 32;
    if (it == 0 || (itg & 7) == 0) {           // qi/g hoisted per k-window
      int k = itg >> 3;
      qi = *(const int4*)(idx_arr + ((size_t)k*NS + sg)*4);
      gg = *(const float4*)(g_arr  + ((size_t)k*NS + sg)*4);
    }
    // ---- A fragments direct from global (coalesced 16B/lane, L2-hot) ----
    uint4 aH[4], aL[4];
    int abase = ((mo*72 + itg)*2 + mw)*4;
    #pragma unroll
    for (int mi = 0; mi < 4; mi++) {
      size_t off = ((size_t)(abase + mi) << 9) + lane*8;
      aH[mi] = *(const uint4*)(A_hi + off);
      aL[mi] = *(const uint4*)(A_lo + off);
    }
    // ---- taps ----
    const float* p0 = xp + qi.x + c0k + cs;
    const float* p1 = xp + qi.y + c0k + cs;
    const float* p2 = xp + qi.z + c0k + cs;
    const float* p3 = xp + qi.w + c0k + cs;
    float4 t0a = *(const float4*)(p0), t0b = *(const float4*)(p0 + 4);
    float4 t1a = *(const float4*)(p1), t1b = *(const float4*)(p1 + 4);
    float4 t2a = *(const float4*)(p2), t2b = *(const float4*)(p2 + 4);
    float4 t3a = *(const float4*)(p3), t3b = *(const float4*)(p3 + 4);
    float v[8];
    v[0] = gg.x*t0a.x + gg.y*t1a.x + gg.z*t2a.x + gg.w*t3a.x;
    v[1] = gg.x*t0a.y + gg.y*t1a.y + gg.z*t2a.y + gg.w*t3a.y;
    v[2] = gg.x*t0a.z + gg.y*t1a.z + gg.z*t2a.z + gg.w*t3a.z;
    v[3] = gg.x*t0a.w + gg.y*t1a.w + gg.z*t2a.w + gg.w*t3a.w;
    v[4] = gg.x*t0b.x + gg.y*t1b.x + gg.z*t2b.x + gg.w*t3b.x;
    v[5] = gg.x*t0b.y + gg.y*t1b.y + gg.z*t2b.y + gg.w*t3b.y;
    v[6] = gg.x*t0b.z + gg.y*t1b.z + gg.z*t2b.z + gg.w*t3b.z;
    v[7] = gg.x*t0b.w + gg.y*t1b.w + gg.z*t2b.w + gg.w*t3b.w;
    u16 hb[8], lb[8];
    #pragma unroll
    for (int j = 0; j < 8; j++) split16(v[j], hb[j], lb[j]);
    uint4 bph, bpl;
    bph.x = (u32)hb[0] | ((u32)hb[1] << 16); bph.y = (u32)hb[2] | ((u32)hb[3] << 16);
    bph.z = (u32)hb[4] | ((u32)hb[5] << 16); bph.w = (u32)hb[6] | ((u32)hb[7] << 16);
    bpl.x = (u32)lb[0] | ((u32)lb[1] << 16); bpl.y = (u32)lb[2] | ((u32)lb[3] << 16);
    bpl.z = (u32)lb[4] | ((u32)lb[5] << 16); bpl.w = (u32)lb[6] | ((u32)lb[7] << 16);
    int buf = it & 1;
    *(uint4*)(&Bh[buf][s_l*40 + cs]) = bph;
    *(uint4*)(&Bl[buf][s_l*40 + cs]) = bpl;
    sync_lds();   // single barrier/iter
    f16x8 bfh[4], bfl[4];
    #pragma unroll
    for (int ni = 0; ni < 4; ni++) {
      int rr = (ni*16 + l16)*40 + quad*8;
      bfh[ni] = *(const f16x8*)(&Bh[buf][rr]);
      bfl[ni] = *(const f16x8*)(&Bl[buf][rr]);
    }
    #pragma unroll
    for (int mi = 0; mi < 4; mi++) {
      f16x8 fh = __builtin_bit_cast(f16x8, aH[mi]);
      f16x8 fl = __builtin_bit_cast(f16x8, aL[mi]);
      #pragma unroll
      for (int ni = 0; ni < 4; ni++) {
        acc[mi][ni] = __builtin_amdgcn_mfma_f32_16x16x32_f16(fh, bfh[ni], acc[mi][ni], 0, 0, 0);
        acc[mi][ni] = __builtin_amdgcn_mfma_f32_16x16x32_f16(fh, bfl[ni], acc[mi][ni], 0, 0, 0);
        acc[mi][ni] = __builtin_amdgcn_mfma_f32_16x16x32_f16(fl, bfh[ni], acc[mi][ni], 0, 0, 0);
      }
    }
  }
  // ---- epilogue: split-K accumulate ----
  #pragma unroll
  for (int mi = 0; mi < 4; mi++)
    #pragma unroll
    for (int ni = 0; ni < 4; ni++) {
      int hw = hw0 + ni*16 + l16;
      #pragma unroll
      for (int rr = 0; rr < 4; rr++) {
        int o = wave*64 + mi*16 + quad*4 + rr;
        atomicAdd(&out[(size_t)(n*OC + o)*HW + hw], acc[mi][ni][rr]);
      }
    }
}

extern "C" void kernel_launch(void* const* d_in, const int* in_sizes, int n_in,
                              void* d_out, int out_size, void* d_ws, size_t ws_size,
                              hipStream_t stream) {
  const float* x      = (const float*)d_in[0];
  const float* w_p    = (const float*)d_in[1];
  const float* b_p    = (const float*)d_in[2];
  const float* w_ad   = (const float*)d_in[3];
  const float* b_ad   = (const float*)d_in[4];
  const float* w_conv = (const float*)d_in[5];
  float* out = (float*)d_out;

  char* ws = (char*)d_ws;
  float* xp      = (float*)(ws + XP_OFF);
  u16*   A_hi    = (u16*)  (ws + AHI_OFF);
  u16*   A_lo    = (u16*)  (ws + ALO_OFF);
  u16*   A2_hi   = (u16*)  (ws + A2HI_OFF);
  u16*   A2_lo   = (u16*)  (ws + A2LO_OFF);
  float* off2    = (float*)(ws + OFF2_OFF);
  int*   idx_arr = (int*)  (ws + IDX_OFF);
  float* g_arr   = (float*)(ws + G_OFF);

  hipMemsetAsync(xp, 0, (size_t)NB*HP*HP*C*sizeof(float), stream);
  hipMemsetAsync(off2, 0, (size_t)21*NS*sizeof(float), stream);
  hipMemsetAsync(out, 0, (size_t)out_size*sizeof(float), stream);

  prep1    <<<1476, 256, 0, stream>>>(x, w_p, w_ad, w_conv, xp, A_hi, A_lo, A2_hi, A2_lo);
  conv_mfma<<<576,  256, 0, stream>>>(A2_hi, A2_lo, xp, off2);
  taps2    <<<648,  256, 0, stream>>>(off2, b_p, b_ad, idx_arr, g_arr);
  gemm_def <<<576,  256, 0, stream>>>(A_hi, A_lo, xp, idx_arr, g_arr, out);
}